// Round 1
// baseline (2273.997 us; speedup 1.0000x reference)
//
#include <hip/hip_runtime.h>
#include <math.h>

#define TOKENS 2048
#define DIM 1024
#define NHEADS 16
#define HEADDIM 64
#define NEXP 32
#define EDIM 128
#define TOPK 8
#define DSHARED 2048
#define RSF_ 2.5f
#define EPS_ 1e-6f

// ---------------- RMSNorm: one block per token ----------------
__global__ __launch_bounds__(256) void rmsnorm_kernel(const float* __restrict__ x,
                                                      const float* __restrict__ w,
                                                      float* __restrict__ out) {
    int row = blockIdx.x;
    const float* xr = x + (long long)row * DIM;
    int t = threadIdx.x;
    float4 xv = ((const float4*)xr)[t];
    float ss = xv.x*xv.x + xv.y*xv.y + xv.z*xv.z + xv.w*xv.w;
    #pragma unroll
    for (int off = 32; off; off >>= 1) ss += __shfl_down(ss, off);
    __shared__ float warps[4];
    if ((t & 63) == 0) warps[t >> 6] = ss;
    __syncthreads();
    float tot = warps[0] + warps[1] + warps[2] + warps[3];
    float scale = rsqrtf(tot / (float)DIM + EPS_);
    float4 wv = ((const float4*)w)[t];
    float4 o;
    o.x = xv.x * scale * wv.x;
    o.y = xv.y * scale * wv.y;
    o.z = xv.z * scale * wv.z;
    o.w = xv.w * scale * wv.w;
    ((float4*)(out + (long long)row * DIM))[t] = o;
}

// ---------------- Generic tiled fp32 GEMM: C = A @ B (row-major) ----------------
// 64x64 tile, BK=16, 256 threads, 4x4 micro-tile. Optional batch (z) strides,
// optional accumulate into C, optional elementwise addend (same layout as C).
template<bool ACC, bool ADD>
__global__ __launch_bounds__(256) void gemm_nn(const float* __restrict__ A, int lda, long long sA,
                                               const float* __restrict__ B, int ldb, long long sB,
                                               float* __restrict__ C, int ldc, long long sC,
                                               const float* __restrict__ Add,
                                               int M, int N, int K) {
    int z = blockIdx.z;
    A += (long long)z * sA;
    B += (long long)z * sB;
    C += (long long)z * sC;
    const int m0 = blockIdx.y * 64;
    const int n0 = blockIdx.x * 64;
    __shared__ float As[16][68];   // As[k][m], padded for b128-aligned reads
    __shared__ float Bs[16][68];   // Bs[k][n]
    const int tid = threadIdx.x;
    const int tx = tid & 15, ty = tid >> 4;
    const int ar = tid >> 2, ac = (tid & 3) * 4;   // A tile: 64 rows x 16 k
    const int br = tid >> 4, bc = (tid & 15) * 4;  // B tile: 16 rows x 64 n
    float acc[4][4] = {};
    for (int k0 = 0; k0 < K; k0 += 16) {
        float4 av = *(const float4*)(A + (long long)(m0 + ar) * lda + k0 + ac);
        float4 bv = *(const float4*)(B + (long long)(k0 + br) * ldb + n0 + bc);
        As[ac + 0][ar] = av.x;
        As[ac + 1][ar] = av.y;
        As[ac + 2][ar] = av.z;
        As[ac + 3][ar] = av.w;
        *(float4*)&Bs[br][bc] = bv;
        __syncthreads();
        #pragma unroll
        for (int kk = 0; kk < 16; ++kk) {
            float4 a = *(const float4*)&As[kk][ty * 4];
            float4 b = *(const float4*)&Bs[kk][tx * 4];
            float aa[4] = {a.x, a.y, a.z, a.w};
            float bb[4] = {b.x, b.y, b.z, b.w};
            #pragma unroll
            for (int i = 0; i < 4; ++i)
                #pragma unroll
                for (int j = 0; j < 4; ++j)
                    acc[i][j] += aa[i] * bb[j];
        }
        __syncthreads();
    }
    #pragma unroll
    for (int i = 0; i < 4; ++i) {
        int m = m0 + ty * 4 + i;
        float* cp = C + (long long)m * ldc + n0 + tx * 4;
        float4 o;
        o.x = acc[i][0]; o.y = acc[i][1]; o.z = acc[i][2]; o.w = acc[i][3];
        if (ACC) {
            float4 c0 = *(const float4*)cp;
            o.x += c0.x; o.y += c0.y; o.z += c0.z; o.w += c0.w;
        }
        if (ADD) {
            const float4 a0 = *(const float4*)(Add + (long long)m * ldc + n0 + tx * 4);
            o.x += a0.x; o.y += a0.y; o.z += a0.z; o.w += a0.w;
        }
        *(float4*)cp = o;
    }
}

// ---------------- QKV post: split heads, l2norm(q,k), RoPE, to [h][s][d] ----------------
__global__ __launch_bounds__(256) void qkv_post(const float* __restrict__ qkv,
                                                float* __restrict__ q,
                                                float* __restrict__ k,
                                                float* __restrict__ v) {
    int lane = threadIdx.x & 63;
    int sh = blockIdx.x * 4 + (threadIdx.x >> 6);  // 0..S*H-1
    int s = sh >> 4;
    int h = sh & 15;
    const float* base = qkv + (long long)s * 3 * DIM;
    float qv = base[h * HEADDIM + lane];
    float kv = base[DIM + h * HEADDIM + lane];
    float vv = base[2 * DIM + h * HEADDIM + lane];
    // l2 normalize q, k over the 64-dim head
    float qs = qv * qv, ks = kv * kv;
    #pragma unroll
    for (int off = 32; off; off >>= 1) {
        qs += __shfl_xor(qs, off);
        ks += __shfl_xor(ks, off);
    }
    qv /= fmaxf(sqrtf(qs), EPS_);
    kv /= fmaxf(sqrtf(ks), EPS_);
    // RoPE
    int i = lane & 31;
    float f = (float)s * powf(10000.0f, -(float)i / 32.0f);
    float c = cosf(f), sn = sinf(f);
    float qo = __shfl_xor(qv, 32);
    float ko = __shfl_xor(kv, 32);
    float sgn = (lane < 32) ? sn : -sn;
    float qr = qv * c + qo * sgn;
    float kr = kv * c + ko * sgn;
    long long o = ((long long)h * TOKENS + s) * HEADDIM + lane;
    q[o] = qr;
    k[o] = kr;
    v[o] = vv;
}

// ---------------- Flash-style causal attention ----------------
// Block: 256 threads (4 waves), handles one head and 32 query rows (8 per wave).
// Iterates 64-key tiles staged in LDS with online softmax.
#define QT 32
#define KT 64
__global__ __launch_bounds__(256) void attn_kernel(const float* __restrict__ q,
                                                   const float* __restrict__ k,
                                                   const float* __restrict__ v,
                                                   float* __restrict__ xo) {
    const int h = blockIdx.y;
    const int q0 = blockIdx.x * QT;
    const int tid = threadIdx.x;
    const int wv = tid >> 6, lane = tid & 63;
    __shared__ float Qs[QT][HEADDIM];
    __shared__ float Ks[KT][HEADDIM + 1];
    __shared__ float Vs[KT][HEADDIM];
    __shared__ float Ps[QT][KT];
    const float* qb = q + ((long long)h * TOKENS + q0) * HEADDIM;
    for (int idx = tid; idx < QT * HEADDIM; idx += 256)
        Qs[idx >> 6][idx & 63] = qb[idx];
    float accr[8], m_[8], l_[8];
    #pragma unroll
    for (int r = 0; r < 8; ++r) { accr[r] = 0.f; m_[r] = -1e30f; l_[r] = 0.f; }
    const int ntiles = q0 / KT + 1;
    for (int kt = 0; kt < ntiles; ++kt) {
        const int j0 = kt * KT;
        __syncthreads();
        for (int idx = tid; idx < KT * HEADDIM; idx += 256) {
            int jj = idx >> 6, d = idx & 63;
            long long g = ((long long)h * TOKENS + j0 + jj) * HEADDIM + d;
            Ks[jj][d] = k[g];
            Vs[jj][d] = v[g];
        }
        __syncthreads();
        float corr[8];
        #pragma unroll
        for (int r = 0; r < 8; ++r) {
            int row = wv * 8 + r, qabs = q0 + row;
            float s;
            if (j0 + lane <= qabs) {
                s = 0.f;
                for (int d = 0; d < HEADDIM; ++d) s += Qs[row][d] * Ks[lane][d];
                s *= 0.125f;
            } else {
                s = -1e30f;
            }
            float mt = s;
            #pragma unroll
            for (int off = 32; off; off >>= 1) mt = fmaxf(mt, __shfl_xor(mt, off));
            float mnew = fmaxf(m_[r], mt);
            float p = __expf(s - mnew);
            corr[r] = __expf(m_[r] - mnew);
            float ps = p;
            #pragma unroll
            for (int off = 32; off; off >>= 1) ps += __shfl_xor(ps, off);
            l_[r] = l_[r] * corr[r] + ps;
            m_[r] = mnew;
            Ps[row][lane] = p;
        }
        __syncthreads();
        #pragma unroll
        for (int r = 0; r < 8; ++r) {
            int row = wv * 8 + r;
            float a = accr[r] * corr[r];
            #pragma unroll 8
            for (int j = 0; j < KT; ++j) a += Ps[row][j] * Vs[j][lane];
            accr[r] = a;
        }
    }
    #pragma unroll
    for (int r = 0; r < 8; ++r) {
        int row = wv * 8 + r;
        xo[(long long)(q0 + row) * DIM + h * HEADDIM + lane] = accr[r] / l_[r];
    }
}

// ---------------- Router: logits, gates, dense w_route (one block per token) ----------------
__global__ __launch_bounds__(256) void router_kernel(const float* __restrict__ xf,
                                                     const float* __restrict__ keys_w,
                                                     const int* __restrict__ idx,
                                                     const float* __restrict__ vals,
                                                     float* __restrict__ w_route) {
    int t = blockIdx.x;
    int tid = threadIdx.x;
    int e = tid & 31, c = tid >> 5;
    const float* xr = xf + (long long)t * DIM;
    float p = 0.f;
    for (int j = 0; j < 128; ++j)
        p += xr[c * 128 + j] * keys_w[(c * 128 + j) * NEXP + e];
    __shared__ float part[8][32];
    part[c][e] = p;
    __syncthreads();
    if (tid < NEXP) {
        float lg = 0.f;
        #pragma unroll
        for (int cc = 0; cc < 8; ++cc) lg += part[cc][tid];
        part[0][tid] = lg;  // logits
    }
    __syncthreads();
    __shared__ float gate_s[TOPK];
    __shared__ int idx_s[TOPK];
    if (tid < TOPK) {
        int ii = idx[t * TOPK + tid];
        float g = vals[t * TOPK + tid] + part[0][ii];
        gate_s[tid] = (1.0f / (1.0f + __expf(-g))) * RSF_;
        idx_s[tid] = ii;
    }
    __syncthreads();
    if (tid < NEXP) {
        float wr = 0.f;
        #pragma unroll
        for (int kk = 0; kk < TOPK; ++kk)
            if (idx_s[kk] == tid) wr += gate_s[kk];
        w_route[(long long)t * NEXP + tid] = wr;
    }
}

// ---------------- h = silu(g) * u * w_route, in place into g ----------------
__global__ void moe_act_kernel(float* __restrict__ g, const float* __restrict__ u,
                               const float* __restrict__ w_route) {
    long long i = (long long)blockIdx.x * 256 + threadIdx.x;  // T*NEXP*EDIM = 8M
    float gv = g[i], uv = u[i];
    int t = (int)(i >> 12);
    int e = (int)(i >> 7) & 31;
    float w = w_route[t * NEXP + e];
    float si = gv / (1.0f + __expf(-gv));
    g[i] = si * uv * w;
}

// ---------------- Transpose W2 [e][d][h] -> W2t [(e*128+h)][d] ----------------
__global__ void transpose_w2(const float* __restrict__ w2, float* __restrict__ w2t) {
    long long i = (long long)blockIdx.x * 256 + threadIdx.x;  // 4M
    int n = (int)(i & 1023);
    int kk = (int)(i >> 10);
    int e = kk >> 7, hh = kk & 127;
    w2t[i] = w2[(long long)e * (DIM * EDIM) + (long long)n * EDIM + hh];
}

// ---------------- Shared-expert SwiGLU: hs = silu(x1) * x2 ----------------
__global__ void swiglu_kernel(const float* __restrict__ up, float* __restrict__ hs) {
    long long i = (long long)blockIdx.x * 256 + threadIdx.x;  // T*DS = 4M
    int t = (int)(i >> 11), j = (int)(i & 2047);
    float x1 = up[(long long)t * (2 * DSHARED) + j];
    float x2 = up[(long long)t * (2 * DSHARED) + DSHARED + j];
    hs[i] = x1 / (1.0f + __expf(-x1)) * x2;
}

// ---------------- Final: out = y_moe + x_ffn_input ----------------
__global__ void final_add(const float* __restrict__ a, const float* __restrict__ b,
                          float* __restrict__ out) {
    long long i = (long long)blockIdx.x * 256 + threadIdx.x;  // 2M
    out[i] = a[i] + b[i];
}

extern "C" void kernel_launch(void* const* d_in, const int* in_sizes, int n_in,
                              void* d_out, int out_size, void* d_ws, size_t ws_size,
                              hipStream_t stream) {
    (void)in_sizes; (void)n_in; (void)out_size; (void)ws_size;
    const float* x_input     = (const float*)d_in[0];
    const int*   indices     = (const int*)d_in[1];
    const float* values      = (const float*)d_in[2];
    const float* w_attn      = (const float*)d_in[3];
    const float* w_attn_o    = (const float*)d_in[4];
    const float* attn_norm_w = (const float*)d_in[5];
    const float* ffn_norm_w  = (const float*)d_in[6];
    const float* ffn_experts = (const float*)d_in[7];
    const float* keys_w      = (const float*)d_in[8];
    const float* w_up        = (const float*)d_in[9];
    const float* w_down      = (const float*)d_in[10];
    float* out = (float*)d_out;
    float* ws  = (float*)d_ws;

    const long long M1 = 1024 * 1024;
    // Lifetime-aliased workspace layout (units of 1M floats):
    float* xffn   = ws + 0 * M1;   // [0,2)   x_ffn_input, live to end
    float* xnorm  = ws + 2 * M1;   // [2,4)   attn-norm out; later xf
    float* xf     = xnorm;
    float* ymoe   = ws + 4 * M1;   // [4,6)   expert+shared accumulator
    float* qkv    = ws + 6 * M1;   // [6,12)  qkv; dead after qkv_post
    float* qh     = ws + 12 * M1;  // [12,14) heads; dead after attention
    float* kh     = ws + 14 * M1;  // [14,16)
    float* vh     = ws + 16 * M1;  // [16,18)
    float* xattn  = ws + 18 * M1;  // [18,20) dead after attn_o gemm
    float* g_all  = ws + 6 * M1;   // [6,14)  reuses qkv/qh (dead)
    float* u_all  = ws + 14 * M1;  // [14,22) reuses kh/vh/xattn (dead)
    float* w2t    = ws + 22 * M1;  // [22,26)
    float* up     = ws + 6 * M1;   // [6,14)  reuses g_all (dead after down gemm)
    float* hs     = ws + 14 * M1;  // [14,18) reuses u_all (dead)
    float* w_route= ws + 26 * M1;  // [26, 26+64K)

    const long long EXP_STRIDE = (long long)NEXP * DIM * EDIM;  // 4M floats

    // 1. attention rmsnorm
    rmsnorm_kernel<<<TOKENS, 256, 0, stream>>>(x_input, attn_norm_w, xnorm);
    // 2. qkv = xnorm @ w_attn  [2048 x 3072]
    {
        dim3 g(3072 / 64, TOKENS / 64, 1);
        gemm_nn<false, false><<<g, 256, 0, stream>>>(xnorm, DIM, 0, w_attn, 3 * DIM, 0,
                                                     qkv, 3 * DIM, 0, nullptr,
                                                     TOKENS, 3 * DIM, DIM);
    }
    // 3. heads + l2norm + rope
    qkv_post<<<(TOKENS * NHEADS) / 4, 256, 0, stream>>>(qkv, qh, kh, vh);
    // 4. causal attention
    {
        dim3 g(TOKENS / QT, NHEADS, 1);
        attn_kernel<<<g, 256, 0, stream>>>(qh, kh, vh, xattn);
    }
    // 5. x_ffn_input = x_attn @ w_attn_o + x_input
    {
        dim3 g(DIM / 64, TOKENS / 64, 1);
        gemm_nn<false, true><<<g, 256, 0, stream>>>(xattn, DIM, 0, w_attn_o, DIM, 0,
                                                    xffn, DIM, 0, x_input,
                                                    TOKENS, DIM, DIM);
    }
    // 6. ffn rmsnorm
    rmsnorm_kernel<<<TOKENS, 256, 0, stream>>>(xffn, ffn_norm_w, xf);
    // 7. router -> dense w_route
    router_kernel<<<TOKENS, 256, 0, stream>>>(xf, keys_w, indices, values, w_route);
    // 8. g = xf @ W0[e]  (batched over 32 experts, C strided into [T, 32*128])
    {
        dim3 g(EDIM / 64, TOKENS / 64, NEXP);
        gemm_nn<false, false><<<g, 256, 0, stream>>>(xf, DIM, 0,
                                                     ffn_experts, EDIM, (long long)DIM * EDIM,
                                                     g_all, NEXP * EDIM, EDIM, nullptr,
                                                     TOKENS, EDIM, DIM);
    }
    // 9. u = xf @ W1[e]
    {
        dim3 g(EDIM / 64, TOKENS / 64, NEXP);
        gemm_nn<false, false><<<g, 256, 0, stream>>>(xf, DIM, 0,
                                                     ffn_experts + EXP_STRIDE, EDIM, (long long)DIM * EDIM,
                                                     u_all, NEXP * EDIM, EDIM, nullptr,
                                                     TOKENS, EDIM, DIM);
    }
    // 10. h = silu(g)*u*w_route (in place into g_all)
    moe_act_kernel<<<(TOKENS * NEXP * EDIM) / 256, 256, 0, stream>>>(g_all, u_all, w_route);
    // 11. W2 transpose to [ (e,h) x d ]
    transpose_w2<<<(NEXP * EDIM * DIM) / 256, 256, 0, stream>>>(ffn_experts + 2 * EXP_STRIDE, w2t);
    // 12. y_moe = h_all @ W2t   [2048 x 1024], K = 4096
    {
        dim3 g(DIM / 64, TOKENS / 64, 1);
        gemm_nn<false, false><<<g, 256, 0, stream>>>(g_all, NEXP * EDIM, 0, w2t, DIM, 0,
                                                     ymoe, DIM, 0, nullptr,
                                                     TOKENS, DIM, NEXP * EDIM);
    }
    // 13. shared expert up: up = xf @ w_up  [2048 x 4096]
    {
        dim3 g((2 * DSHARED) / 64, TOKENS / 64, 1);
        gemm_nn<false, false><<<g, 256, 0, stream>>>(xf, DIM, 0, w_up, 2 * DSHARED, 0,
                                                     up, 2 * DSHARED, 0, nullptr,
                                                     TOKENS, 2 * DSHARED, DIM);
    }
    // 14. hs = silu(x1)*x2
    swiglu_kernel<<<(TOKENS * DSHARED) / 256, 256, 0, stream>>>(up, hs);
    // 15. y_moe += hs @ w_down  [2048 x 1024], K = 2048
    {
        dim3 g(DIM / 64, TOKENS / 64, 1);
        gemm_nn<true, false><<<g, 256, 0, stream>>>(hs, DSHARED, 0, w_down, DIM, 0,
                                                    ymoe, DIM, 0, nullptr,
                                                    TOKENS, DIM, DSHARED);
    }
    // 16. out = y_moe + x_ffn_input
    final_add<<<(TOKENS * DIM) / 256, 256, 0, stream>>>(ymoe, xffn, out);
}

// Round 2
// 1337.869 us; speedup vs baseline: 1.6997x; 1.6997x over previous
//
#include <hip/hip_runtime.h>
#include <math.h>

#define TOKENS 2048
#define DIM 1024
#define NHEADS 16
#define HEADDIM 64
#define NEXP 32
#define EDIM 128
#define TOPK 8
#define DSHARED 2048
#define RSF_ 2.5f
#define EPS_ 1e-6f

using bf8  = __attribute__((ext_vector_type(8))) short;   // 8 bf16 in 4 VGPRs
using f32x4 = __attribute__((ext_vector_type(4))) float;  // MFMA accumulator

__device__ __forceinline__ short f2bf(float f) {
    unsigned u = __float_as_uint(f);
    unsigned r = (u + 0x7fffu + ((u >> 16) & 1u)) >> 16;
    return (short)r;
}
__device__ __forceinline__ float bf2f(short s) {
    return __uint_as_float(((unsigned)(unsigned short)s) << 16);
}

// ---------------- RMSNorm: one block per token, bf16 output ----------------
__global__ __launch_bounds__(256) void rmsnorm_kernel(const float* __restrict__ x,
                                                      const float* __restrict__ w,
                                                      short* __restrict__ out) {
    int row = blockIdx.x;
    const float* xr = x + (long long)row * DIM;
    int t = threadIdx.x;
    float4 xv = ((const float4*)xr)[t];
    float ss = xv.x*xv.x + xv.y*xv.y + xv.z*xv.z + xv.w*xv.w;
    #pragma unroll
    for (int off = 32; off; off >>= 1) ss += __shfl_down(ss, off);
    __shared__ float warps[4];
    if ((t & 63) == 0) warps[t >> 6] = ss;
    __syncthreads();
    float tot = warps[0] + warps[1] + warps[2] + warps[3];
    float scale = rsqrtf(tot / (float)DIM + EPS_);
    float4 wv = ((const float4*)w)[t];
    short4 o;
    o.x = f2bf(xv.x * scale * wv.x);
    o.y = f2bf(xv.y * scale * wv.y);
    o.z = f2bf(xv.z * scale * wv.z);
    o.w = f2bf(xv.w * scale * wv.w);
    ((short4*)(out + (long long)row * DIM))[t] = o;
}

// ---------------- Transpose + convert: fp32 in[K][N] -> bf16 out[N][K] ----------------
__global__ __launch_bounds__(256) void tconv(const float* __restrict__ in, long long sin,
                                             short* __restrict__ out, long long sout,
                                             int K, int N) {
    in  += (long long)blockIdx.z * sin;
    out += (long long)blockIdx.z * sout;
    __shared__ float t[32][33];
    int n0 = blockIdx.x * 32, k0 = blockIdx.y * 32;
    int tx = threadIdx.x & 31, ty = threadIdx.x >> 5;  // ty 0..7
    #pragma unroll
    for (int r = ty; r < 32; r += 8)
        t[r][tx] = in[(long long)(k0 + r) * N + n0 + tx];
    __syncthreads();
    #pragma unroll
    for (int r = ty; r < 32; r += 8)
        out[(long long)(n0 + r) * K + k0 + tx] = f2bf(t[tx][r]);
}

// W2 [e][d][h] fp32 -> bf16 [d][(e*128+h)]  (copy with row restride, both sides coalesced)
__global__ void w2conv(const float* __restrict__ in, short* __restrict__ out) {
    long long i = (long long)blockIdx.x * 256 + threadIdx.x;  // 32*1024*128 = 4M
    int e = (int)(i >> 17);
    int d = (int)(i >> 7) & 1023;
    int h = (int)(i & 127);
    out[(long long)d * (NEXP * EDIM) + e * EDIM + h] = f2bf(in[i]);
}

// ---------------- bf16 MFMA GEMM: C[M][N] (+=) A[M][K] @ Bt[N][K]^T ----------------
// 128x128 tile, BK=32, 256 threads (4 waves in 2x2), 4x4 MFMA 16x16x32 per wave.
template<bool ACC, bool ADD>
__global__ __launch_bounds__(256) void gemm_bf16(const short* __restrict__ A, int lda, long long sA,
                                                 const short* __restrict__ Bt, int ldb, long long sBt,
                                                 float* __restrict__ C, int ldc, long long sC,
                                                 const float* __restrict__ Add,
                                                 int M, int N, int K) {
    A  += (long long)blockIdx.z * sA;
    Bt += (long long)blockIdx.z * sBt;
    C  += (long long)blockIdx.z * sC;
    const int m0 = blockIdx.y * 128;
    const int n0 = blockIdx.x * 128;
    __shared__ short As[128 * 32];
    __shared__ short Bs[128 * 32];
    const int tid = threadIdx.x;
    const int lane = tid & 63;
    const int w = tid >> 6;
    const int wm = (w >> 1) * 64, wn = (w & 1) * 64;
    // staging: 16B chunks; 512 chunks per 8KB tile; this thread does chunk tid and tid+256
    const int r0 = tid >> 2, c0 = (tid & 3) * 8;
    const short* Ap = A + (long long)m0 * lda;
    const short* Bp = Bt + (long long)n0 * ldb;
    f32x4 acc[4][4];
    #pragma unroll
    for (int i = 0; i < 4; ++i)
        #pragma unroll
        for (int j = 0; j < 4; ++j) { f32x4 z = {0.f, 0.f, 0.f, 0.f}; acc[i][j] = z; }
    const int qa = (lane >> 4) * 8;   // k offset within BK for this lane's fragment
    const int ra = lane & 15;         // row/col within 16-tile
    for (int k0 = 0; k0 < K; k0 += 32) {
        int4 a0 = *(const int4*)(Ap + (long long)r0 * lda + k0 + c0);
        int4 a1 = *(const int4*)(Ap + (long long)(r0 + 64) * lda + k0 + c0);
        int4 b0 = *(const int4*)(Bp + (long long)r0 * ldb + k0 + c0);
        int4 b1 = *(const int4*)(Bp + (long long)(r0 + 64) * ldb + k0 + c0);
        __syncthreads();
        *(int4*)(As + r0 * 32 + c0) = a0;
        *(int4*)(As + (r0 + 64) * 32 + c0) = a1;
        *(int4*)(Bs + r0 * 32 + c0) = b0;
        *(int4*)(Bs + (r0 + 64) * 32 + c0) = b1;
        __syncthreads();
        bf8 af[4], bfv[4];
        #pragma unroll
        for (int i = 0; i < 4; ++i) af[i]  = *(const bf8*)(As + (wm + i * 16 + ra) * 32 + qa);
        #pragma unroll
        for (int j = 0; j < 4; ++j) bfv[j] = *(const bf8*)(Bs + (wn + j * 16 + ra) * 32 + qa);
        #pragma unroll
        for (int i = 0; i < 4; ++i)
            #pragma unroll
            for (int j = 0; j < 4; ++j)
                acc[i][j] = __builtin_amdgcn_mfma_f32_16x16x32_bf16(af[i], bfv[j], acc[i][j], 0, 0, 0);
    }
    // C/D layout: col = lane&15, row = (lane>>4)*4 + reg
    const int cr = (lane >> 4) * 4, cc = lane & 15;
    #pragma unroll
    for (int i = 0; i < 4; ++i) {
        #pragma unroll
        for (int r = 0; r < 4; ++r) {
            int row = m0 + wm + i * 16 + cr + r;
            float* crow = C + (long long)row * ldc + n0 + wn + cc;
            #pragma unroll
            for (int j = 0; j < 4; ++j) {
                float v = acc[i][j][r];
                if (ACC) v += crow[j * 16];
                if (ADD) v += Add[(long long)row * ldc + n0 + wn + cc + j * 16];
                crow[j * 16] = v;
            }
        }
    }
}

// ---------------- QKV post: split heads, l2norm(q,k), RoPE, to [h][s][d] ----------------
__global__ __launch_bounds__(256) void qkv_post(const float* __restrict__ qkv,
                                                float* __restrict__ q,
                                                float* __restrict__ k,
                                                float* __restrict__ v) {
    int lane = threadIdx.x & 63;
    int sh = blockIdx.x * 4 + (threadIdx.x >> 6);
    int s = sh >> 4;
    int h = sh & 15;
    const float* base = qkv + (long long)s * 3 * DIM;
    float qv = base[h * HEADDIM + lane];
    float kv = base[DIM + h * HEADDIM + lane];
    float vv = base[2 * DIM + h * HEADDIM + lane];
    float qs = qv * qv, ks = kv * kv;
    #pragma unroll
    for (int off = 32; off; off >>= 1) {
        qs += __shfl_xor(qs, off);
        ks += __shfl_xor(ks, off);
    }
    qv /= fmaxf(sqrtf(qs), EPS_);
    kv /= fmaxf(sqrtf(ks), EPS_);
    int i = lane & 31;
    float f = (float)s * powf(10000.0f, -(float)i / 32.0f);
    float c = cosf(f), sn = sinf(f);
    float qo = __shfl_xor(qv, 32);
    float ko = __shfl_xor(kv, 32);
    float sgn = (lane < 32) ? sn : -sn;
    float qr = qv * c + qo * sgn;
    float kr = kv * c + ko * sgn;
    long long o = ((long long)h * TOKENS + s) * HEADDIM + lane;
    q[o] = qr;
    k[o] = kr;
    v[o] = vv;
}

// ---------------- Flash-style causal attention (fp32), bf16 output ----------------
#define QT 32
#define KT 64
__global__ __launch_bounds__(256) void attn_kernel(const float* __restrict__ q,
                                                   const float* __restrict__ k,
                                                   const float* __restrict__ v,
                                                   short* __restrict__ xo) {
    const int h = blockIdx.y;
    // longest blocks (largest q0) first to kill the drain tail
    const int q0 = ((int)gridDim.x - 1 - (int)blockIdx.x) * QT;
    const int tid = threadIdx.x;
    const int wv = tid >> 6, lane = tid & 63;
    __shared__ float Qs[QT][HEADDIM];
    __shared__ float Ks[KT][HEADDIM + 1];
    __shared__ float Vs[KT][HEADDIM];
    __shared__ float Ps[QT][KT];
    const float* qb = q + ((long long)h * TOKENS + q0) * HEADDIM;
    for (int idx = tid; idx < QT * HEADDIM; idx += 256)
        Qs[idx >> 6][idx & 63] = qb[idx];
    float accr[8], m_[8], l_[8];
    #pragma unroll
    for (int r = 0; r < 8; ++r) { accr[r] = 0.f; m_[r] = -1e30f; l_[r] = 0.f; }
    const int ntiles = q0 / KT + 1;
    for (int kt = 0; kt < ntiles; ++kt) {
        const int j0 = kt * KT;
        __syncthreads();
        for (int idx = tid; idx < KT * HEADDIM; idx += 256) {
            int jj = idx >> 6, d = idx & 63;
            long long g = ((long long)h * TOKENS + j0 + jj) * HEADDIM + d;
            Ks[jj][d] = k[g];
            Vs[jj][d] = v[g];
        }
        __syncthreads();
        float corr[8];
        #pragma unroll
        for (int r = 0; r < 8; ++r) {
            int row = wv * 8 + r, qabs = q0 + row;
            float s;
            if (j0 + lane <= qabs) {
                s = 0.f;
                for (int d = 0; d < HEADDIM; ++d) s += Qs[row][d] * Ks[lane][d];
                s *= 0.125f;
            } else {
                s = -1e30f;
            }
            float mt = s;
            #pragma unroll
            for (int off = 32; off; off >>= 1) mt = fmaxf(mt, __shfl_xor(mt, off));
            float mnew = fmaxf(m_[r], mt);
            float p = __expf(s - mnew);
            corr[r] = __expf(m_[r] - mnew);
            float ps = p;
            #pragma unroll
            for (int off = 32; off; off >>= 1) ps += __shfl_xor(ps, off);
            l_[r] = l_[r] * corr[r] + ps;
            m_[r] = mnew;
            Ps[row][lane] = p;
        }
        __syncthreads();
        #pragma unroll
        for (int r = 0; r < 8; ++r) {
            int row = wv * 8 + r;
            float a = accr[r] * corr[r];
            #pragma unroll 8
            for (int j = 0; j < KT; ++j) a += Ps[row][j] * Vs[j][lane];
            accr[r] = a;
        }
    }
    #pragma unroll
    for (int r = 0; r < 8; ++r) {
        int row = wv * 8 + r;
        xo[(long long)(q0 + row) * DIM + h * HEADDIM + lane] = f2bf(accr[r] / l_[r]);
    }
}

// ---------------- Router (bf16 x input) ----------------
__global__ __launch_bounds__(256) void router_kernel(const short* __restrict__ xf,
                                                     const float* __restrict__ keys_w,
                                                     const int* __restrict__ idx,
                                                     const float* __restrict__ vals,
                                                     float* __restrict__ w_route) {
    int t = blockIdx.x;
    int tid = threadIdx.x;
    int e = tid & 31, c = tid >> 5;
    const short* xr = xf + (long long)t * DIM;
    float p = 0.f;
    for (int j = 0; j < 128; ++j)
        p += bf2f(xr[c * 128 + j]) * keys_w[(c * 128 + j) * NEXP + e];
    __shared__ float part[8][32];
    part[c][e] = p;
    __syncthreads();
    if (tid < NEXP) {
        float lg = 0.f;
        #pragma unroll
        for (int cc = 0; cc < 8; ++cc) lg += part[cc][tid];
        part[0][tid] = lg;
    }
    __syncthreads();
    __shared__ float gate_s[TOPK];
    __shared__ int idx_s[TOPK];
    if (tid < TOPK) {
        int ii = idx[t * TOPK + tid];
        float g = vals[t * TOPK + tid] + part[0][ii];
        gate_s[tid] = (1.0f / (1.0f + __expf(-g))) * RSF_;
        idx_s[tid] = ii;
    }
    __syncthreads();
    if (tid < NEXP) {
        float wr = 0.f;
        #pragma unroll
        for (int kk = 0; kk < TOPK; ++kk)
            if (idx_s[kk] == tid) wr += gate_s[kk];
        w_route[(long long)t * NEXP + tid] = wr;
    }
}

// ---------------- h = silu(g) * u * w_route -> bf16 ----------------
__global__ void moe_act_kernel(const float* __restrict__ g, const float* __restrict__ u,
                               const float* __restrict__ w_route, short* __restrict__ hb) {
    long long i = (long long)blockIdx.x * 256 + threadIdx.x;  // T*NEXP*EDIM = 8M
    float gv = g[i], uv = u[i];
    int t = (int)(i >> 12);
    int e = (int)(i >> 7) & 31;
    float w = w_route[t * NEXP + e];
    float si = gv / (1.0f + __expf(-gv));
    hb[i] = f2bf(si * uv * w);
}

// ---------------- Shared-expert SwiGLU -> bf16 ----------------
__global__ void swiglu_kernel(const float* __restrict__ up, short* __restrict__ hs) {
    long long i = (long long)blockIdx.x * 256 + threadIdx.x;  // T*DS = 4M
    int t = (int)(i >> 11), j = (int)(i & 2047);
    float x1 = up[(long long)t * (2 * DSHARED) + j];
    float x2 = up[(long long)t * (2 * DSHARED) + DSHARED + j];
    hs[i] = f2bf(x1 / (1.0f + __expf(-x1)) * x2);
}

// ---------------- Final: out = y_moe + x_ffn_input ----------------
__global__ void final_add(const float* __restrict__ a, const float* __restrict__ b,
                          float* __restrict__ out) {
    long long i = (long long)blockIdx.x * 256 + threadIdx.x;  // 2M
    out[i] = a[i] + b[i];
}

extern "C" void kernel_launch(void* const* d_in, const int* in_sizes, int n_in,
                              void* d_out, int out_size, void* d_ws, size_t ws_size,
                              hipStream_t stream) {
    (void)in_sizes; (void)n_in; (void)out_size; (void)ws_size;
    const float* x_input     = (const float*)d_in[0];
    const int*   indices     = (const int*)d_in[1];
    const float* values      = (const float*)d_in[2];
    const float* w_attn      = (const float*)d_in[3];
    const float* w_attn_o    = (const float*)d_in[4];
    const float* attn_norm_w = (const float*)d_in[5];
    const float* ffn_norm_w  = (const float*)d_in[6];
    const float* ffn_experts = (const float*)d_in[7];
    const float* keys_w      = (const float*)d_in[8];
    const float* w_up        = (const float*)d_in[9];
    const float* w_down      = (const float*)d_in[10];
    float* out = (float*)d_out;
    float* ws  = (float*)d_ws;

    const long long M1 = 1024 * 1024;
    // Workspace (float units, lifetime-aliased; max extent 26M floats = 104MB):
    float* xffn    = ws + 0 * M1;               // [0,2)   live attn_o -> end
    float* ymoe    = ws + 2 * M1;               // [2,4)
    short* xa_bf   = (short*)(ws + 4 * M1);     // [4,4.5)
    short* xf_bf   = (short*)(ws + 4 * M1 + M1 / 2);  // [4.5,5)
    short* xattn_bf= (short*)(ws + 5 * M1);     // [5,5.5)
    float* w_route = ws + 5 * M1 + M1 / 2;      // [5.5,5.57)
    float* qkv     = ws + 6 * M1;               // [6,12)  phase A
    float* qh      = ws + 12 * M1;              // [12,14)
    float* kh      = ws + 14 * M1;              // [14,16)
    float* vh      = ws + 16 * M1;              // [16,18)
    short* wattn_t = (short*)(ws + 18 * M1);    // [18,19.5)
    short* wattno_t= (short*)(ws + 19 * M1 + M1 / 2);  // [19.5,20)
    float* g_all   = ws + 6 * M1;               // [6,14)  phase B (qkv,qh dead)
    float* u_all   = ws + 14 * M1;              // [14,22) (kh,vh,w*_t dead)
    short* h_bf    = (short*)(ws + 22 * M1);    // [22,24)
    short* wt      = (short*)(ws + 24 * M1);    // [24,26) W0t then W1t
    short* w2t     = (short*)(ws + 6 * M1);     // [6,8)   after g/u fp32 dead
    short* wupt    = (short*)(ws + 8 * M1);     // [8,10)
    short* wdownt  = (short*)(ws + 10 * M1);    // [10,11)
    short* hs_bf   = (short*)(ws + 12 * M1);    // [12,12.5)
    float* up      = ws + 14 * M1;              // [14,22) after u_all dead

    const long long EXP_STRIDE = (long long)NEXP * DIM * EDIM;  // 4M

    // ---- phase A: attention ----
    tconv<<<dim3(3072 / 32, DIM / 32, 1), 256, 0, stream>>>(w_attn, 0, wattn_t, 0, DIM, 3 * DIM);
    rmsnorm_kernel<<<TOKENS, 256, 0, stream>>>(x_input, attn_norm_w, xa_bf);
    gemm_bf16<false, false><<<dim3(3072 / 128, TOKENS / 128, 1), 256, 0, stream>>>(
        xa_bf, DIM, 0, wattn_t, DIM, 0, qkv, 3 * DIM, 0, nullptr, TOKENS, 3 * DIM, DIM);
    qkv_post<<<(TOKENS * NHEADS) / 4, 256, 0, stream>>>(qkv, qh, kh, vh);
    attn_kernel<<<dim3(TOKENS / QT, NHEADS, 1), 256, 0, stream>>>(qh, kh, vh, xattn_bf);
    tconv<<<dim3(DIM / 32, DIM / 32, 1), 256, 0, stream>>>(w_attn_o, 0, wattno_t, 0, DIM, DIM);
    gemm_bf16<false, true><<<dim3(DIM / 128, TOKENS / 128, 1), 256, 0, stream>>>(
        xattn_bf, DIM, 0, wattno_t, DIM, 0, xffn, DIM, 0, x_input, TOKENS, DIM, DIM);

    // ---- phase B: router + experts ----
    rmsnorm_kernel<<<TOKENS, 256, 0, stream>>>(xffn, ffn_norm_w, xf_bf);
    router_kernel<<<TOKENS, 256, 0, stream>>>(xf_bf, keys_w, indices, values, w_route);
    tconv<<<dim3(EDIM / 32, DIM / 32, NEXP), 256, 0, stream>>>(
        ffn_experts, (long long)DIM * EDIM, wt, (long long)DIM * EDIM, DIM, EDIM);
    gemm_bf16<false, false><<<dim3(1, TOKENS / 128, NEXP), 256, 0, stream>>>(
        xf_bf, DIM, 0, wt, DIM, (long long)DIM * EDIM, g_all, NEXP * EDIM, EDIM, nullptr,
        TOKENS, EDIM, DIM);
    tconv<<<dim3(EDIM / 32, DIM / 32, NEXP), 256, 0, stream>>>(
        ffn_experts + EXP_STRIDE, (long long)DIM * EDIM, wt, (long long)DIM * EDIM, DIM, EDIM);
    gemm_bf16<false, false><<<dim3(1, TOKENS / 128, NEXP), 256, 0, stream>>>(
        xf_bf, DIM, 0, wt, DIM, (long long)DIM * EDIM, u_all, NEXP * EDIM, EDIM, nullptr,
        TOKENS, EDIM, DIM);
    moe_act_kernel<<<(TOKENS * NEXP * EDIM) / 256, 256, 0, stream>>>(g_all, u_all, w_route, h_bf);
    w2conv<<<(NEXP * DIM * EDIM) / 256, 256, 0, stream>>>(ffn_experts + 2 * EXP_STRIDE, w2t);
    gemm_bf16<false, false><<<dim3(DIM / 128, TOKENS / 128, 1), 256, 0, stream>>>(
        h_bf, NEXP * EDIM, 0, w2t, NEXP * EDIM, 0, ymoe, DIM, 0, nullptr,
        TOKENS, DIM, NEXP * EDIM);

    // ---- phase C: shared expert ----
    tconv<<<dim3((2 * DSHARED) / 32, DIM / 32, 1), 256, 0, stream>>>(w_up, 0, wupt, 0, DIM, 2 * DSHARED);
    gemm_bf16<false, false><<<dim3((2 * DSHARED) / 128, TOKENS / 128, 1), 256, 0, stream>>>(
        xf_bf, DIM, 0, wupt, DIM, 0, up, 2 * DSHARED, 0, nullptr, TOKENS, 2 * DSHARED, DIM);
    swiglu_kernel<<<(TOKENS * DSHARED) / 256, 256, 0, stream>>>(up, hs_bf);
    tconv<<<dim3(DIM / 32, DSHARED / 32, 1), 256, 0, stream>>>(w_down, 0, wdownt, 0, DSHARED, DIM);
    gemm_bf16<true, false><<<dim3(DIM / 128, TOKENS / 128, 1), 256, 0, stream>>>(
        hs_bf, DSHARED, 0, wdownt, DSHARED, 0, ymoe, DIM, 0, nullptr, TOKENS, DIM, DSHARED);

    // ---- final residual ----
    final_add<<<(TOKENS * DIM) / 256, 256, 0, stream>>>(ymoe, xffn, out);
}

// Round 3
// 631.180 us; speedup vs baseline: 3.6028x; 2.1196x over previous
//
#include <hip/hip_runtime.h>
#include <math.h>

#define TOKENS 2048
#define DIM 1024
#define NHEADS 16
#define HEADDIM 64
#define NEXP 32
#define EDIM 128
#define TOPK 8
#define DSHARED 2048
#define RSF_ 2.5f
#define EPS_ 1e-6f

using bf8  = __attribute__((ext_vector_type(8))) short;   // 8 bf16 in 4 VGPRs
using f32x4 = __attribute__((ext_vector_type(4))) float;  // MFMA accumulator

__device__ __forceinline__ short f2bf(float f) {
    unsigned u = __float_as_uint(f);
    unsigned r = (u + 0x7fffu + ((u >> 16) & 1u)) >> 16;
    return (short)r;
}
__device__ __forceinline__ float bf2f(short s) {
    return __uint_as_float(((unsigned)(unsigned short)s) << 16);
}

// ---------------- RMSNorm: one block per token, bf16 output ----------------
__global__ __launch_bounds__(256) void rmsnorm_kernel(const float* __restrict__ x,
                                                      const float* __restrict__ w,
                                                      short* __restrict__ out) {
    int row = blockIdx.x;
    const float* xr = x + (long long)row * DIM;
    int t = threadIdx.x;
    float4 xv = ((const float4*)xr)[t];
    float ss = xv.x*xv.x + xv.y*xv.y + xv.z*xv.z + xv.w*xv.w;
    #pragma unroll
    for (int off = 32; off; off >>= 1) ss += __shfl_down(ss, off);
    __shared__ float warps[4];
    if ((t & 63) == 0) warps[t >> 6] = ss;
    __syncthreads();
    float tot = warps[0] + warps[1] + warps[2] + warps[3];
    float scale = rsqrtf(tot / (float)DIM + EPS_);
    float4 wv = ((const float4*)w)[t];
    short4 o;
    o.x = f2bf(xv.x * scale * wv.x);
    o.y = f2bf(xv.y * scale * wv.y);
    o.z = f2bf(xv.z * scale * wv.z);
    o.w = f2bf(xv.w * scale * wv.w);
    ((short4*)(out + (long long)row * DIM))[t] = o;
}

// ---------------- Transpose + convert: fp32 in[K][N] -> bf16 out[N][K] ----------------
__global__ __launch_bounds__(256) void tconv(const float* __restrict__ in, long long sin,
                                             short* __restrict__ out, long long sout,
                                             int K, int N) {
    in  += (long long)blockIdx.z * sin;
    out += (long long)blockIdx.z * sout;
    __shared__ float t[32][33];
    int n0 = blockIdx.x * 32, k0 = blockIdx.y * 32;
    int tx = threadIdx.x & 31, ty = threadIdx.x >> 5;  // ty 0..7
    #pragma unroll
    for (int r = ty; r < 32; r += 8)
        t[r][tx] = in[(long long)(k0 + r) * N + n0 + tx];
    __syncthreads();
    #pragma unroll
    for (int r = ty; r < 32; r += 8)
        out[(long long)(n0 + r) * K + k0 + tx] = f2bf(t[tx][r]);
}

// W2 [e][d][h] fp32 -> bf16 [d][(e*128+h)]
__global__ void w2conv(const float* __restrict__ in, short* __restrict__ out) {
    long long i = (long long)blockIdx.x * 256 + threadIdx.x;  // 4M
    int e = (int)(i >> 17);
    int d = (int)(i >> 7) & 1023;
    int h = (int)(i & 127);
    out[(long long)d * (NEXP * EDIM) + e * EDIM + h] = f2bf(in[i]);
}

// ---------------- bf16 MFMA GEMM: C[M][N] (+=) A[M][K] @ Bt[N][K]^T ----------------
template<bool ACC, bool ADD>
__global__ __launch_bounds__(256) void gemm_bf16(const short* __restrict__ A, int lda, long long sA,
                                                 const short* __restrict__ Bt, int ldb, long long sBt,
                                                 float* __restrict__ C, int ldc, long long sC,
                                                 const float* __restrict__ Add,
                                                 int M, int N, int K) {
    A  += (long long)blockIdx.z * sA;
    Bt += (long long)blockIdx.z * sBt;
    C  += (long long)blockIdx.z * sC;
    const int m0 = blockIdx.y * 128;
    const int n0 = blockIdx.x * 128;
    __shared__ short As[128 * 32];
    __shared__ short Bs[128 * 32];
    const int tid = threadIdx.x;
    const int lane = tid & 63;
    const int w = tid >> 6;
    const int wm = (w >> 1) * 64, wn = (w & 1) * 64;
    const int r0 = tid >> 2, c0 = (tid & 3) * 8;
    const short* Ap = A + (long long)m0 * lda;
    const short* Bp = Bt + (long long)n0 * ldb;
    f32x4 acc[4][4];
    #pragma unroll
    for (int i = 0; i < 4; ++i)
        #pragma unroll
        for (int j = 0; j < 4; ++j) { f32x4 z = {0.f, 0.f, 0.f, 0.f}; acc[i][j] = z; }
    const int qa = (lane >> 4) * 8;
    const int ra = lane & 15;
    for (int k0 = 0; k0 < K; k0 += 32) {
        int4 a0 = *(const int4*)(Ap + (long long)r0 * lda + k0 + c0);
        int4 a1 = *(const int4*)(Ap + (long long)(r0 + 64) * lda + k0 + c0);
        int4 b0 = *(const int4*)(Bp + (long long)r0 * ldb + k0 + c0);
        int4 b1 = *(const int4*)(Bp + (long long)(r0 + 64) * ldb + k0 + c0);
        __syncthreads();
        *(int4*)(As + r0 * 32 + c0) = a0;
        *(int4*)(As + (r0 + 64) * 32 + c0) = a1;
        *(int4*)(Bs + r0 * 32 + c0) = b0;
        *(int4*)(Bs + (r0 + 64) * 32 + c0) = b1;
        __syncthreads();
        bf8 af[4], bfv[4];
        #pragma unroll
        for (int i = 0; i < 4; ++i) af[i]  = *(const bf8*)(As + (wm + i * 16 + ra) * 32 + qa);
        #pragma unroll
        for (int j = 0; j < 4; ++j) bfv[j] = *(const bf8*)(Bs + (wn + j * 16 + ra) * 32 + qa);
        #pragma unroll
        for (int i = 0; i < 4; ++i)
            #pragma unroll
            for (int j = 0; j < 4; ++j)
                acc[i][j] = __builtin_amdgcn_mfma_f32_16x16x32_bf16(af[i], bfv[j], acc[i][j], 0, 0, 0);
    }
    const int cr = (lane >> 4) * 4, cc = lane & 15;
    #pragma unroll
    for (int i = 0; i < 4; ++i) {
        #pragma unroll
        for (int r = 0; r < 4; ++r) {
            int row = m0 + wm + i * 16 + cr + r;
            float* crow = C + (long long)row * ldc + n0 + wn + cc;
            #pragma unroll
            for (int j = 0; j < 4; ++j) {
                float v = acc[i][j][r];
                if (ACC) v += crow[j * 16];
                if (ADD) v += Add[(long long)row * ldc + n0 + wn + cc + j * 16];
                crow[j * 16] = v;
            }
        }
    }
}

// ---------------- QKV post: split heads, l2norm(q,k), RoPE -> bf16 [h][s][64] ----------------
__global__ __launch_bounds__(256) void qkv_post(const float* __restrict__ qkv,
                                                short* __restrict__ q,
                                                short* __restrict__ k) {
    int lane = threadIdx.x & 63;
    int sh = blockIdx.x * 4 + (threadIdx.x >> 6);
    int s = sh >> 4;
    int h = sh & 15;
    const float* base = qkv + (long long)s * 3 * DIM;
    float qv = base[h * HEADDIM + lane];
    float kv = base[DIM + h * HEADDIM + lane];
    float qs = qv * qv, ks = kv * kv;
    #pragma unroll
    for (int off = 32; off; off >>= 1) {
        qs += __shfl_xor(qs, off);
        ks += __shfl_xor(ks, off);
    }
    qv /= fmaxf(sqrtf(qs), EPS_);
    kv /= fmaxf(sqrtf(ks), EPS_);
    int i = lane & 31;
    float f = (float)s * powf(10000.0f, -(float)i / 32.0f);
    float c = cosf(f), sn = sinf(f);
    float qo = __shfl_xor(qv, 32);
    float ko = __shfl_xor(kv, 32);
    float sgn = (lane < 32) ? sn : -sn;
    float qr = qv * c + qo * sgn;
    float kr = kv * c + ko * sgn;
    long long o = ((long long)h * TOKENS + s) * HEADDIM + lane;
    q[o] = f2bf(qr);
    k[o] = f2bf(kr);
}

// ---------------- V transpose: qkv fp32 [s][3D] -> vt bf16 [h][64][2048] ----------------
__global__ __launch_bounds__(256) void vtrans(const float* __restrict__ qkv,
                                              short* __restrict__ vt) {
    int h = blockIdx.z;
    int s0 = blockIdx.x * 32, d0 = blockIdx.y * 32;
    __shared__ float t[32][33];
    int tx = threadIdx.x & 31, ty = threadIdx.x >> 5;
    #pragma unroll
    for (int r = ty; r < 32; r += 8)
        t[r][tx] = qkv[(long long)(s0 + r) * (3 * DIM) + 2 * DIM + h * HEADDIM + d0 + tx];
    __syncthreads();
    #pragma unroll
    for (int r = ty; r < 32; r += 8)
        vt[((long long)h * HEADDIM + d0 + r) * TOKENS + s0 + tx] = f2bf(t[tx][r]);
}

// ---------------- MFMA flash attention: 64 q-rows/block, 64-key tiles ----------------
// q,k bf16 [h][s][64]; vt bf16 [h][64][s]; out bf16 [s][1024]
#define ALD 72   // padded LDS row (bf16 units)
__global__ __launch_bounds__(256) void attn_kernel(const short* __restrict__ q,
                                                   const short* __restrict__ k,
                                                   const short* __restrict__ vt,
                                                   short* __restrict__ xo) {
    const int h = blockIdx.y;
    const int q0 = ((int)gridDim.x - 1 - (int)blockIdx.x) * 64;  // longest first
    const int tid = threadIdx.x;
    const int w = tid >> 6, lane = tid & 63;
    const int col = lane & 15, quad = lane >> 4;
    __shared__ short Ks[64 * ALD];
    __shared__ short Vts[64 * ALD];
    __shared__ short Ps[4 * 16 * ALD];
    short* Pw = Ps + w * 16 * ALD;
    const int qbase = q0 + w * 16;
    // Q fragments (A-layout): row = col, k = quad*8 (+32)
    bf8 qf[2];
    #pragma unroll
    for (int ks = 0; ks < 2; ++ks)
        qf[ks] = *(const bf8*)(q + ((long long)h * TOKENS + qbase + col) * HEADDIM + ks * 32 + quad * 8);
    f32x4 o_[4];
    float m_[4], l_[4];
    #pragma unroll
    for (int n = 0; n < 4; ++n) { f32x4 z = {0.f, 0.f, 0.f, 0.f}; o_[n] = z; }
    #pragma unroll
    for (int r = 0; r < 4; ++r) { m_[r] = -1e30f; l_[r] = 0.f; }
    const int ntiles = q0 / 64 + 1;
    for (int kt = 0; kt < ntiles; ++kt) {
        const int j0 = kt * 64;
        // stage K tile [64 keys][64 d] and Vt tile [64 d][64 keys]
        int4 kv[2], vv[2];
        #pragma unroll
        for (int rr = 0; rr < 2; ++rr) {
            int idx = tid + rr * 256;
            int row = idx >> 3, c8 = (idx & 7) * 8;
            kv[rr] = *(const int4*)(k + ((long long)h * TOKENS + j0 + row) * HEADDIM + c8);
            vv[rr] = *(const int4*)(vt + ((long long)h * HEADDIM + row) * TOKENS + j0 + c8);
        }
        __syncthreads();
        #pragma unroll
        for (int rr = 0; rr < 2; ++rr) {
            int idx = tid + rr * 256;
            int row = idx >> 3, c8 = (idx & 7) * 8;
            *(int4*)(Ks + row * ALD + c8) = kv[rr];
            *(int4*)(Vts + row * ALD + c8) = vv[rr];
        }
        __syncthreads();
        // S = Q K^T (per wave: [16 q][64 keys])
        f32x4 sacc[4];
        #pragma unroll
        for (int n = 0; n < 4; ++n) { f32x4 z = {0.f, 0.f, 0.f, 0.f}; sacc[n] = z; }
        #pragma unroll
        for (int ks = 0; ks < 2; ++ks) {
            #pragma unroll
            for (int nt = 0; nt < 4; ++nt) {
                bf8 kf = *(const bf8*)(Ks + (nt * 16 + col) * ALD + ks * 32 + quad * 8);
                sacc[nt] = __builtin_amdgcn_mfma_f32_16x16x32_bf16(qf[ks], kf, sacc[nt], 0, 0, 0);
            }
        }
        // softmax (rows live in 16-lane groups; row = quad*4+r, col = key)
        float sv[4][4];
        const bool diag = (j0 + 64 > qbase);
        #pragma unroll
        for (int nt = 0; nt < 4; ++nt)
            #pragma unroll
            for (int r = 0; r < 4; ++r) {
                float s = sacc[nt][r] * 0.125f;
                if (diag && (j0 + nt * 16 + col > qbase + quad * 4 + r)) s = -1e30f;
                sv[nt][r] = s;
            }
        #pragma unroll
        for (int r = 0; r < 4; ++r) {
            float mx = fmaxf(fmaxf(sv[0][r], sv[1][r]), fmaxf(sv[2][r], sv[3][r]));
            #pragma unroll
            for (int off = 1; off < 16; off <<= 1) mx = fmaxf(mx, __shfl_xor(mx, off));
            float mnew = fmaxf(m_[r], mx);
            float corr = __expf(m_[r] - mnew);
            m_[r] = mnew;
            float psum = 0.f;
            #pragma unroll
            for (int nt = 0; nt < 4; ++nt) {
                float p = __expf(sv[nt][r] - mnew);
                sv[nt][r] = p;
                psum += p;
            }
            #pragma unroll
            for (int off = 1; off < 16; off <<= 1) psum += __shfl_xor(psum, off);
            l_[r] = l_[r] * corr + psum;
            #pragma unroll
            for (int n = 0; n < 4; ++n) o_[n][r] *= corr;
            // P row (bf16) into wave-private LDS
            #pragma unroll
            for (int nt = 0; nt < 4; ++nt)
                Pw[(quad * 4 + r) * ALD + nt * 16 + col] = f2bf(sv[nt][r]);
        }
        // O += P V  (A = P [16 q][64 key], B = V via Vt rows)
        #pragma unroll
        for (int ks = 0; ks < 2; ++ks) {
            bf8 pf = *(const bf8*)(Pw + col * ALD + ks * 32 + quad * 8);
            #pragma unroll
            for (int nt = 0; nt < 4; ++nt) {
                bf8 vf = *(const bf8*)(Vts + (nt * 16 + col) * ALD + ks * 32 + quad * 8);
                o_[nt] = __builtin_amdgcn_mfma_f32_16x16x32_bf16(pf, vf, o_[nt], 0, 0, 0);
            }
        }
    }
    // write out: row = qbase + quad*4 + r, col = h*64 + nt*16 + col
    #pragma unroll
    for (int nt = 0; nt < 4; ++nt)
        #pragma unroll
        for (int r = 0; r < 4; ++r) {
            int row = qbase + quad * 4 + r;
            xo[(long long)row * DIM + h * HEADDIM + nt * 16 + col] = f2bf(o_[nt][r] / l_[r]);
        }
}

// ---------------- Router (bf16 x input) ----------------
__global__ __launch_bounds__(256) void router_kernel(const short* __restrict__ xf,
                                                     const float* __restrict__ keys_w,
                                                     const int* __restrict__ idx,
                                                     const float* __restrict__ vals,
                                                     float* __restrict__ w_route) {
    int t = blockIdx.x;
    int tid = threadIdx.x;
    int e = tid & 31, c = tid >> 5;
    const short* xr = xf + (long long)t * DIM;
    float p = 0.f;
    for (int j = 0; j < 128; ++j)
        p += bf2f(xr[c * 128 + j]) * keys_w[(c * 128 + j) * NEXP + e];
    __shared__ float part[8][32];
    part[c][e] = p;
    __syncthreads();
    if (tid < NEXP) {
        float lg = 0.f;
        #pragma unroll
        for (int cc = 0; cc < 8; ++cc) lg += part[cc][tid];
        part[0][tid] = lg;
    }
    __syncthreads();
    __shared__ float gate_s[TOPK];
    __shared__ int idx_s[TOPK];
    if (tid < TOPK) {
        int ii = idx[t * TOPK + tid];
        float g = vals[t * TOPK + tid] + part[0][ii];
        gate_s[tid] = (1.0f / (1.0f + __expf(-g))) * RSF_;
        idx_s[tid] = ii;
    }
    __syncthreads();
    if (tid < NEXP) {
        float wr = 0.f;
        #pragma unroll
        for (int kk = 0; kk < TOPK; ++kk)
            if (idx_s[kk] == tid) wr += gate_s[kk];
        w_route[(long long)t * NEXP + tid] = wr;
    }
}

// ---------------- h = silu(g) * u * w_route -> bf16 ----------------
__global__ void moe_act_kernel(const float* __restrict__ g, const float* __restrict__ u,
                               const float* __restrict__ w_route, short* __restrict__ hb) {
    long long i = (long long)blockIdx.x * 256 + threadIdx.x;  // 8M
    float gv = g[i], uv = u[i];
    int t = (int)(i >> 12);
    int e = (int)(i >> 7) & 31;
    float w = w_route[t * NEXP + e];
    float si = gv / (1.0f + __expf(-gv));
    hb[i] = f2bf(si * uv * w);
}

// ---------------- Shared-expert SwiGLU -> bf16 ----------------
__global__ void swiglu_kernel(const float* __restrict__ up, short* __restrict__ hs) {
    long long i = (long long)blockIdx.x * 256 + threadIdx.x;  // 4M
    int t = (int)(i >> 11), j = (int)(i & 2047);
    float x1 = up[(long long)t * (2 * DSHARED) + j];
    float x2 = up[(long long)t * (2 * DSHARED) + DSHARED + j];
    hs[i] = f2bf(x1 / (1.0f + __expf(-x1)) * x2);
}

// ---------------- Final: out = y_moe + x_ffn_input ----------------
__global__ void final_add(const float* __restrict__ a, const float* __restrict__ b,
                          float* __restrict__ out) {
    long long i = (long long)blockIdx.x * 256 + threadIdx.x;  // 2M
    out[i] = a[i] + b[i];
}

extern "C" void kernel_launch(void* const* d_in, const int* in_sizes, int n_in,
                              void* d_out, int out_size, void* d_ws, size_t ws_size,
                              hipStream_t stream) {
    (void)in_sizes; (void)n_in; (void)out_size; (void)ws_size;
    const float* x_input     = (const float*)d_in[0];
    const int*   indices     = (const int*)d_in[1];
    const float* values      = (const float*)d_in[2];
    const float* w_attn      = (const float*)d_in[3];
    const float* w_attn_o    = (const float*)d_in[4];
    const float* attn_norm_w = (const float*)d_in[5];
    const float* ffn_norm_w  = (const float*)d_in[6];
    const float* ffn_experts = (const float*)d_in[7];
    const float* keys_w      = (const float*)d_in[8];
    const float* w_up        = (const float*)d_in[9];
    const float* w_down      = (const float*)d_in[10];
    float* out = (float*)d_out;
    float* ws  = (float*)d_ws;

    const long long M1 = 1024 * 1024;
    float* xffn    = ws + 0 * M1;               // [0,2)
    float* ymoe    = ws + 2 * M1;               // [2,4)
    short* xa_bf   = (short*)(ws + 4 * M1);     // [4,4.5)
    short* xf_bf   = (short*)(ws + 4 * M1 + M1 / 2);  // [4.5,5)
    short* xattn_bf= (short*)(ws + 5 * M1);     // [5,5.5)
    float* w_route = ws + 5 * M1 + M1 / 2;      // [5.5,5.57)
    float* qkv     = ws + 6 * M1;               // [6,12)  phase A
    short* qh_bf   = (short*)(ws + 12 * M1);    // [12,12.5)
    short* kh_bf   = (short*)(ws + 12 * M1 + M1 / 2);  // [12.5,13)
    short* vt_bf   = (short*)(ws + 13 * M1);    // [13,13.5)
    short* wattn_t = (short*)(ws + 18 * M1);    // [18,19.5)
    short* wattno_t= (short*)(ws + 19 * M1 + M1 / 2);  // [19.5,20)
    float* g_all   = ws + 6 * M1;               // [6,14)  phase B
    float* u_all   = ws + 14 * M1;              // [14,22)
    short* h_bf    = (short*)(ws + 22 * M1);    // [22,24)
    short* wt      = (short*)(ws + 24 * M1);    // [24,26)
    short* w2t     = (short*)(ws + 6 * M1);     // [6,8)
    short* wupt    = (short*)(ws + 8 * M1);     // [8,10)
    short* wdownt  = (short*)(ws + 10 * M1);    // [10,11)
    short* hs_bf   = (short*)(ws + 12 * M1);    // [12,12.5)
    float* up      = ws + 14 * M1;              // [14,22)

    const long long EXP_STRIDE = (long long)NEXP * DIM * EDIM;  // 4M

    // ---- phase A: attention ----
    tconv<<<dim3(3072 / 32, DIM / 32, 1), 256, 0, stream>>>(w_attn, 0, wattn_t, 0, DIM, 3 * DIM);
    rmsnorm_kernel<<<TOKENS, 256, 0, stream>>>(x_input, attn_norm_w, xa_bf);
    gemm_bf16<false, false><<<dim3(3072 / 128, TOKENS / 128, 1), 256, 0, stream>>>(
        xa_bf, DIM, 0, wattn_t, DIM, 0, qkv, 3 * DIM, 0, nullptr, TOKENS, 3 * DIM, DIM);
    qkv_post<<<(TOKENS * NHEADS) / 4, 256, 0, stream>>>(qkv, qh_bf, kh_bf);
    vtrans<<<dim3(TOKENS / 32, HEADDIM / 32, NHEADS), 256, 0, stream>>>(qkv, vt_bf);
    attn_kernel<<<dim3(TOKENS / 64, NHEADS, 1), 256, 0, stream>>>(qh_bf, kh_bf, vt_bf, xattn_bf);
    tconv<<<dim3(DIM / 32, DIM / 32, 1), 256, 0, stream>>>(w_attn_o, 0, wattno_t, 0, DIM, DIM);
    gemm_bf16<false, true><<<dim3(DIM / 128, TOKENS / 128, 1), 256, 0, stream>>>(
        xattn_bf, DIM, 0, wattno_t, DIM, 0, xffn, DIM, 0, x_input, TOKENS, DIM, DIM);

    // ---- phase B: router + experts ----
    rmsnorm_kernel<<<TOKENS, 256, 0, stream>>>(xffn, ffn_norm_w, xf_bf);
    router_kernel<<<TOKENS, 256, 0, stream>>>(xf_bf, keys_w, indices, values, w_route);
    tconv<<<dim3(EDIM / 32, DIM / 32, NEXP), 256, 0, stream>>>(
        ffn_experts, (long long)DIM * EDIM, wt, (long long)DIM * EDIM, DIM, EDIM);
    gemm_bf16<false, false><<<dim3(1, TOKENS / 128, NEXP), 256, 0, stream>>>(
        xf_bf, DIM, 0, wt, DIM, (long long)DIM * EDIM, g_all, NEXP * EDIM, EDIM, nullptr,
        TOKENS, EDIM, DIM);
    tconv<<<dim3(EDIM / 32, DIM / 32, NEXP), 256, 0, stream>>>(
        ffn_experts + EXP_STRIDE, (long long)DIM * EDIM, wt, (long long)DIM * EDIM, DIM, EDIM);
    gemm_bf16<false, false><<<dim3(1, TOKENS / 128, NEXP), 256, 0, stream>>>(
        xf_bf, DIM, 0, wt, DIM, (long long)DIM * EDIM, u_all, NEXP * EDIM, EDIM, nullptr,
        TOKENS, EDIM, DIM);
    moe_act_kernel<<<(TOKENS * NEXP * EDIM) / 256, 256, 0, stream>>>(g_all, u_all, w_route, h_bf);
    w2conv<<<(NEXP * DIM * EDIM) / 256, 256, 0, stream>>>(ffn_experts + 2 * EXP_STRIDE, w2t);
    gemm_bf16<false, false><<<dim3(DIM / 128, TOKENS / 128, 1), 256, 0, stream>>>(
        h_bf, NEXP * EDIM, 0, w2t, NEXP * EDIM, 0, ymoe, DIM, 0, nullptr,
        TOKENS, DIM, NEXP * EDIM);

    // ---- phase C: shared expert ----
    tconv<<<dim3((2 * DSHARED) / 32, DIM / 32, 1), 256, 0, stream>>>(w_up, 0, wupt, 0, DIM, 2 * DSHARED);
    gemm_bf16<false, false><<<dim3((2 * DSHARED) / 128, TOKENS / 128, 1), 256, 0, stream>>>(
        xf_bf, DIM, 0, wupt, DIM, 0, up, 2 * DSHARED, 0, nullptr, TOKENS, 2 * DSHARED, DIM);
    swiglu_kernel<<<(TOKENS * DSHARED) / 256, 256, 0, stream>>>(up, hs_bf);
    tconv<<<dim3(DIM / 32, DSHARED / 32, 1), 256, 0, stream>>>(w_down, 0, wdownt, 0, DSHARED, DIM);
    gemm_bf16<true, false><<<dim3(DIM / 128, TOKENS / 128, 1), 256, 0, stream>>>(
        hs_bf, DSHARED, 0, wdownt, DSHARED, 0, ymoe, DIM, 0, nullptr, TOKENS, DIM, DSHARED);

    // ---- final residual ----
    final_add<<<(TOKENS * DIM) / 256, 256, 0, stream>>>(ymoe, xffn, out);
}

// Round 4
// 625.313 us; speedup vs baseline: 3.6366x; 1.0094x over previous
//
#include <hip/hip_runtime.h>
#include <math.h>

#define TOKENS 2048
#define DIM 1024
#define NHEADS 16
#define HEADDIM 64
#define NEXP 32
#define EDIM 128
#define TOPK 8
#define DSHARED 2048
#define RSF_ 2.5f
#define EPS_ 1e-6f

using bf8  = __attribute__((ext_vector_type(8))) short;   // 8 bf16 in 4 VGPRs
using f32x4 = __attribute__((ext_vector_type(4))) float;  // MFMA accumulator

__device__ __forceinline__ short f2bf(float f) {
    unsigned u = __float_as_uint(f);
    unsigned r = (u + 0x7fffu + ((u >> 16) & 1u)) >> 16;
    return (short)r;
}
__device__ __forceinline__ float bf2f(short s) {
    return __uint_as_float(((unsigned)(unsigned short)s) << 16);
}

// Direct global->LDS DMA, 16B per lane. LDS dest = wave-uniform base + lane*16.
__device__ __forceinline__ void async16(const short* g, const short* l) {
    __builtin_amdgcn_global_load_lds(
        (const __attribute__((address_space(1))) void*)(unsigned long long)g,
        (__attribute__((address_space(3))) void*)(unsigned)(unsigned long long)l,
        16, 0, 0);
}

// ---------------- RMSNorm: one block per token, bf16 output ----------------
__global__ __launch_bounds__(256) void rmsnorm_kernel(const float* __restrict__ x,
                                                      const float* __restrict__ w,
                                                      short* __restrict__ out) {
    int row = blockIdx.x;
    const float* xr = x + (long long)row * DIM;
    int t = threadIdx.x;
    float4 xv = ((const float4*)xr)[t];
    float ss = xv.x*xv.x + xv.y*xv.y + xv.z*xv.z + xv.w*xv.w;
    #pragma unroll
    for (int off = 32; off; off >>= 1) ss += __shfl_down(ss, off);
    __shared__ float warps[4];
    if ((t & 63) == 0) warps[t >> 6] = ss;
    __syncthreads();
    float tot = warps[0] + warps[1] + warps[2] + warps[3];
    float scale = rsqrtf(tot / (float)DIM + EPS_);
    float4 wv = ((const float4*)w)[t];
    short4 o;
    o.x = f2bf(xv.x * scale * wv.x);
    o.y = f2bf(xv.y * scale * wv.y);
    o.z = f2bf(xv.z * scale * wv.z);
    o.w = f2bf(xv.w * scale * wv.w);
    ((short4*)(out + (long long)row * DIM))[t] = o;
}

// ---------------- Transpose + convert: fp32 in[K][N] -> bf16 out[N][K] ----------------
__global__ __launch_bounds__(256) void tconv(const float* __restrict__ in, long long sin,
                                             short* __restrict__ out, long long sout,
                                             int K, int N) {
    in  += (long long)blockIdx.z * sin;
    out += (long long)blockIdx.z * sout;
    __shared__ float t[32][33];
    int n0 = blockIdx.x * 32, k0 = blockIdx.y * 32;
    int tx = threadIdx.x & 31, ty = threadIdx.x >> 5;  // ty 0..7
    #pragma unroll
    for (int r = ty; r < 32; r += 8)
        t[r][tx] = in[(long long)(k0 + r) * N + n0 + tx];
    __syncthreads();
    #pragma unroll
    for (int r = ty; r < 32; r += 8)
        out[(long long)(n0 + r) * K + k0 + tx] = f2bf(t[tx][r]);
}

// W2 [e][d][h] fp32 -> bf16 [d][(e*128+h)]
__global__ void w2conv(const float* __restrict__ in, short* __restrict__ out) {
    long long i = (long long)blockIdx.x * 256 + threadIdx.x;  // 4M
    int e = (int)(i >> 17);
    int d = (int)(i >> 7) & 1023;
    int h = (int)(i & 127);
    out[(long long)d * (NEXP * EDIM) + e * EDIM + h] = f2bf(in[i]);
}

// ---------------- bf16 MFMA GEMM: C[M][N] (+=) A[M][K] @ Bt[N][K]^T ----------------
// 128x128 tile, BK=32, 256 threads (4 waves), async global->LDS staging (m97-style).
template<bool ACC, bool ADD>
__global__ __launch_bounds__(256) void gemm_bf16(const short* __restrict__ A, int lda, long long sA,
                                                 const short* __restrict__ Bt, int ldb, long long sBt,
                                                 float* __restrict__ C, int ldc, long long sC,
                                                 const float* __restrict__ Add,
                                                 int M, int N, int K) {
    A  += (long long)blockIdx.z * sA;
    Bt += (long long)blockIdx.z * sBt;
    C  += (long long)blockIdx.z * sC;
    const int m0 = blockIdx.y * 128;
    const int n0 = blockIdx.x * 128;
    __shared__ short As[128 * 32];
    __shared__ short Bs[128 * 32];
    const int tid = threadIdx.x;
    const int lane = tid & 63;
    const int w = tid >> 6;
    const int wm = (w >> 1) * 64, wn = (w & 1) * 64;
    const short* Ap = A + (long long)m0 * lda;
    const short* Bp = Bt + (long long)n0 * ldb;
    // async staging: wave w stages rows [w*32, w*32+32) of each tile as two
    // 16-row (1KB) chunks; lane covers (row = lane>>2, 16B at col (lane&3)*8)
    const int srow = lane >> 2;
    const int scol = (lane & 3) * 8;
    const short* ag0 = Ap + (long long)(w * 32 + srow) * lda + scol;
    const short* ag1 = ag0 + (long long)16 * lda;
    const short* bg0 = Bp + (long long)(w * 32 + srow) * ldb + scol;
    const short* bg1 = bg0 + (long long)16 * ldb;
    const short* lA0 = As + w * 1024;
    const short* lA1 = As + w * 1024 + 512;
    const short* lB0 = Bs + w * 1024;
    const short* lB1 = Bs + w * 1024 + 512;
    f32x4 acc[4][4];
    #pragma unroll
    for (int i = 0; i < 4; ++i)
        #pragma unroll
        for (int j = 0; j < 4; ++j) { f32x4 z = {0.f, 0.f, 0.f, 0.f}; acc[i][j] = z; }
    const int qa = (lane >> 4) * 8;
    const int ra = lane & 15;
    for (int k0 = 0; k0 < K; k0 += 32) {
        async16(ag0 + k0, lA0);
        async16(ag1 + k0, lA1);
        async16(bg0 + k0, lB0);
        async16(bg1 + k0, lB1);
        __syncthreads();   // drains vmcnt -> tiles resident
        bf8 af[4], bfv[4];
        #pragma unroll
        for (int i = 0; i < 4; ++i) af[i]  = *(const bf8*)(As + (wm + i * 16 + ra) * 32 + qa);
        #pragma unroll
        for (int j = 0; j < 4; ++j) bfv[j] = *(const bf8*)(Bs + (wn + j * 16 + ra) * 32 + qa);
        #pragma unroll
        for (int i = 0; i < 4; ++i)
            #pragma unroll
            for (int j = 0; j < 4; ++j)
                acc[i][j] = __builtin_amdgcn_mfma_f32_16x16x32_bf16(af[i], bfv[j], acc[i][j], 0, 0, 0);
        __syncthreads();   // all reads done before next DMA overwrites
    }
    const int cr = (lane >> 4) * 4, cc = lane & 15;
    #pragma unroll
    for (int i = 0; i < 4; ++i) {
        #pragma unroll
        for (int r = 0; r < 4; ++r) {
            int row = m0 + wm + i * 16 + cr + r;
            float* crow = C + (long long)row * ldc + n0 + wn + cc;
            #pragma unroll
            for (int j = 0; j < 4; ++j) {
                float v = acc[i][j][r];
                if (ACC) v += crow[j * 16];
                if (ADD) v += Add[(long long)row * ldc + n0 + wn + cc + j * 16];
                crow[j * 16] = v;
            }
        }
    }
}

// ---------------- QKV post: split heads, l2norm(q,k), RoPE -> bf16 [h][s][64] ----------------
__global__ __launch_bounds__(256) void qkv_post(const float* __restrict__ qkv,
                                                short* __restrict__ q,
                                                short* __restrict__ k) {
    int lane = threadIdx.x & 63;
    int sh = blockIdx.x * 4 + (threadIdx.x >> 6);
    int s = sh >> 4;
    int h = sh & 15;
    const float* base = qkv + (long long)s * 3 * DIM;
    float qv = base[h * HEADDIM + lane];
    float kv = base[DIM + h * HEADDIM + lane];
    float qs = qv * qv, ks = kv * kv;
    #pragma unroll
    for (int off = 32; off; off >>= 1) {
        qs += __shfl_xor(qs, off);
        ks += __shfl_xor(ks, off);
    }
    qv /= fmaxf(sqrtf(qs), EPS_);
    kv /= fmaxf(sqrtf(ks), EPS_);
    int i = lane & 31;
    float f = (float)s * powf(10000.0f, -(float)i / 32.0f);
    float c = cosf(f), sn = sinf(f);
    float qo = __shfl_xor(qv, 32);
    float ko = __shfl_xor(kv, 32);
    float sgn = (lane < 32) ? sn : -sn;
    float qr = qv * c + qo * sgn;
    float kr = kv * c + ko * sgn;
    long long o = ((long long)h * TOKENS + s) * HEADDIM + lane;
    q[o] = f2bf(qr);
    k[o] = f2bf(kr);
}

// ---------------- V transpose: qkv fp32 [s][3D] -> vt bf16 [h][64][2048] ----------------
__global__ __launch_bounds__(256) void vtrans(const float* __restrict__ qkv,
                                              short* __restrict__ vt) {
    int h = blockIdx.z;
    int s0 = blockIdx.x * 32, d0 = blockIdx.y * 32;
    __shared__ float t[32][33];
    int tx = threadIdx.x & 31, ty = threadIdx.x >> 5;
    #pragma unroll
    for (int r = ty; r < 32; r += 8)
        t[r][tx] = qkv[(long long)(s0 + r) * (3 * DIM) + 2 * DIM + h * HEADDIM + d0 + tx];
    __syncthreads();
    #pragma unroll
    for (int r = ty; r < 32; r += 8)
        vt[((long long)h * HEADDIM + d0 + r) * TOKENS + s0 + tx] = f2bf(t[tx][r]);
}

// ---------------- MFMA flash attention: 64 q-rows/block, 64-key tiles ----------------
#define ALD 72   // padded LDS row (bf16 units)
__global__ __launch_bounds__(256) void attn_kernel(const short* __restrict__ q,
                                                   const short* __restrict__ k,
                                                   const short* __restrict__ vt,
                                                   short* __restrict__ xo) {
    const int h = blockIdx.y;
    const int q0 = ((int)gridDim.x - 1 - (int)blockIdx.x) * 64;  // longest first
    const int tid = threadIdx.x;
    const int w = tid >> 6, lane = tid & 63;
    const int col = lane & 15, quad = lane >> 4;
    __shared__ short Ks[64 * ALD];
    __shared__ short Vts[64 * ALD];
    __shared__ short Ps[4 * 16 * ALD];
    short* Pw = Ps + w * 16 * ALD;
    const int qbase = q0 + w * 16;
    bf8 qf[2];
    #pragma unroll
    for (int ks = 0; ks < 2; ++ks)
        qf[ks] = *(const bf8*)(q + ((long long)h * TOKENS + qbase + col) * HEADDIM + ks * 32 + quad * 8);
    f32x4 o_[4];
    float m_[4], l_[4];
    #pragma unroll
    for (int n = 0; n < 4; ++n) { f32x4 z = {0.f, 0.f, 0.f, 0.f}; o_[n] = z; }
    #pragma unroll
    for (int r = 0; r < 4; ++r) { m_[r] = -1e30f; l_[r] = 0.f; }
    const int ntiles = q0 / 64 + 1;
    for (int kt = 0; kt < ntiles; ++kt) {
        const int j0 = kt * 64;
        int4 kv[2], vv[2];
        #pragma unroll
        for (int rr = 0; rr < 2; ++rr) {
            int idx = tid + rr * 256;
            int row = idx >> 3, c8 = (idx & 7) * 8;
            kv[rr] = *(const int4*)(k + ((long long)h * TOKENS + j0 + row) * HEADDIM + c8);
            vv[rr] = *(const int4*)(vt + ((long long)h * HEADDIM + row) * TOKENS + j0 + c8);
        }
        __syncthreads();
        #pragma unroll
        for (int rr = 0; rr < 2; ++rr) {
            int idx = tid + rr * 256;
            int row = idx >> 3, c8 = (idx & 7) * 8;
            *(int4*)(Ks + row * ALD + c8) = kv[rr];
            *(int4*)(Vts + row * ALD + c8) = vv[rr];
        }
        __syncthreads();
        f32x4 sacc[4];
        #pragma unroll
        for (int n = 0; n < 4; ++n) { f32x4 z = {0.f, 0.f, 0.f, 0.f}; sacc[n] = z; }
        #pragma unroll
        for (int ks = 0; ks < 2; ++ks) {
            #pragma unroll
            for (int nt = 0; nt < 4; ++nt) {
                bf8 kf = *(const bf8*)(Ks + (nt * 16 + col) * ALD + ks * 32 + quad * 8);
                sacc[nt] = __builtin_amdgcn_mfma_f32_16x16x32_bf16(qf[ks], kf, sacc[nt], 0, 0, 0);
            }
        }
        float sv[4][4];
        const bool diag = (j0 + 64 > qbase);
        #pragma unroll
        for (int nt = 0; nt < 4; ++nt)
            #pragma unroll
            for (int r = 0; r < 4; ++r) {
                float s = sacc[nt][r] * 0.125f;
                if (diag && (j0 + nt * 16 + col > qbase + quad * 4 + r)) s = -1e30f;
                sv[nt][r] = s;
            }
        #pragma unroll
        for (int r = 0; r < 4; ++r) {
            float mx = fmaxf(fmaxf(sv[0][r], sv[1][r]), fmaxf(sv[2][r], sv[3][r]));
            #pragma unroll
            for (int off = 1; off < 16; off <<= 1) mx = fmaxf(mx, __shfl_xor(mx, off));
            float mnew = fmaxf(m_[r], mx);
            float corr = __expf(m_[r] - mnew);
            m_[r] = mnew;
            float psum = 0.f;
            #pragma unroll
            for (int nt = 0; nt < 4; ++nt) {
                float p = __expf(sv[nt][r] - mnew);
                sv[nt][r] = p;
                psum += p;
            }
            #pragma unroll
            for (int off = 1; off < 16; off <<= 1) psum += __shfl_xor(psum, off);
            l_[r] = l_[r] * corr + psum;
            #pragma unroll
            for (int n = 0; n < 4; ++n) o_[n][r] *= corr;
            #pragma unroll
            for (int nt = 0; nt < 4; ++nt)
                Pw[(quad * 4 + r) * ALD + nt * 16 + col] = f2bf(sv[nt][r]);
        }
        #pragma unroll
        for (int ks = 0; ks < 2; ++ks) {
            bf8 pf = *(const bf8*)(Pw + col * ALD + ks * 32 + quad * 8);
            #pragma unroll
            for (int nt = 0; nt < 4; ++nt) {
                bf8 vf = *(const bf8*)(Vts + (nt * 16 + col) * ALD + ks * 32 + quad * 8);
                o_[nt] = __builtin_amdgcn_mfma_f32_16x16x32_bf16(pf, vf, o_[nt], 0, 0, 0);
            }
        }
    }
    #pragma unroll
    for (int nt = 0; nt < 4; ++nt)
        #pragma unroll
        for (int r = 0; r < 4; ++r) {
            int row = qbase + quad * 4 + r;
            xo[(long long)row * DIM + h * HEADDIM + nt * 16 + col] = f2bf(o_[nt][r] / l_[r]);
        }
}

// ---------------- Router (bf16 x input) ----------------
__global__ __launch_bounds__(256) void router_kernel(const short* __restrict__ xf,
                                                     const float* __restrict__ keys_w,
                                                     const int* __restrict__ idx,
                                                     const float* __restrict__ vals,
                                                     float* __restrict__ w_route) {
    int t = blockIdx.x;
    int tid = threadIdx.x;
    int e = tid & 31, c = tid >> 5;
    const short* xr = xf + (long long)t * DIM;
    float p = 0.f;
    for (int j = 0; j < 128; ++j)
        p += bf2f(xr[c * 128 + j]) * keys_w[(c * 128 + j) * NEXP + e];
    __shared__ float part[8][32];
    part[c][e] = p;
    __syncthreads();
    if (tid < NEXP) {
        float lg = 0.f;
        #pragma unroll
        for (int cc = 0; cc < 8; ++cc) lg += part[cc][tid];
        part[0][tid] = lg;
    }
    __syncthreads();
    __shared__ float gate_s[TOPK];
    __shared__ int idx_s[TOPK];
    if (tid < TOPK) {
        int ii = idx[t * TOPK + tid];
        float g = vals[t * TOPK + tid] + part[0][ii];
        gate_s[tid] = (1.0f / (1.0f + __expf(-g))) * RSF_;
        idx_s[tid] = ii;
    }
    __syncthreads();
    if (tid < NEXP) {
        float wr = 0.f;
        #pragma unroll
        for (int kk = 0; kk < TOPK; ++kk)
            if (idx_s[kk] == tid) wr += gate_s[kk];
        w_route[(long long)t * NEXP + tid] = wr;
    }
}

// ---------------- h = silu(g) * u * w_route -> bf16 ----------------
__global__ void moe_act_kernel(const float* __restrict__ g, const float* __restrict__ u,
                               const float* __restrict__ w_route, short* __restrict__ hb) {
    long long i = (long long)blockIdx.x * 256 + threadIdx.x;  // 8M
    float gv = g[i], uv = u[i];
    int t = (int)(i >> 12);
    int e = (int)(i >> 7) & 31;
    float w = w_route[t * NEXP + e];
    float si = gv / (1.0f + __expf(-gv));
    hb[i] = f2bf(si * uv * w);
}

// ---------------- Shared-expert SwiGLU -> bf16 ----------------
__global__ void swiglu_kernel(const float* __restrict__ up, short* __restrict__ hs) {
    long long i = (long long)blockIdx.x * 256 + threadIdx.x;  // 4M
    int t = (int)(i >> 11), j = (int)(i & 2047);
    float x1 = up[(long long)t * (2 * DSHARED) + j];
    float x2 = up[(long long)t * (2 * DSHARED) + DSHARED + j];
    hs[i] = f2bf(x1 / (1.0f + __expf(-x1)) * x2);
}

// ---------------- Final: out = y_moe + x_ffn_input ----------------
__global__ void final_add(const float* __restrict__ a, const float* __restrict__ b,
                          float* __restrict__ out) {
    long long i = (long long)blockIdx.x * 256 + threadIdx.x;  // 2M
    out[i] = a[i] + b[i];
}

extern "C" void kernel_launch(void* const* d_in, const int* in_sizes, int n_in,
                              void* d_out, int out_size, void* d_ws, size_t ws_size,
                              hipStream_t stream) {
    (void)in_sizes; (void)n_in; (void)out_size; (void)ws_size;
    const float* x_input     = (const float*)d_in[0];
    const int*   indices     = (const int*)d_in[1];
    const float* values      = (const float*)d_in[2];
    const float* w_attn      = (const float*)d_in[3];
    const float* w_attn_o    = (const float*)d_in[4];
    const float* attn_norm_w = (const float*)d_in[5];
    const float* ffn_norm_w  = (const float*)d_in[6];
    const float* ffn_experts = (const float*)d_in[7];
    const float* keys_w      = (const float*)d_in[8];
    const float* w_up        = (const float*)d_in[9];
    const float* w_down      = (const float*)d_in[10];
    float* out = (float*)d_out;
    float* ws  = (float*)d_ws;

    const long long M1 = 1024 * 1024;
    float* xffn    = ws + 0 * M1;               // [0,2)
    float* ymoe    = ws + 2 * M1;               // [2,4)
    short* xa_bf   = (short*)(ws + 4 * M1);     // [4,4.5)
    short* xf_bf   = (short*)(ws + 4 * M1 + M1 / 2);  // [4.5,5)
    short* xattn_bf= (short*)(ws + 5 * M1);     // [5,5.5)
    float* w_route = ws + 5 * M1 + M1 / 2;      // [5.5,5.57)
    float* qkv     = ws + 6 * M1;               // [6,12)  phase A
    short* qh_bf   = (short*)(ws + 12 * M1);    // [12,12.5)
    short* kh_bf   = (short*)(ws + 12 * M1 + M1 / 2);  // [12.5,13)
    short* vt_bf   = (short*)(ws + 13 * M1);    // [13,13.5)
    short* wattn_t = (short*)(ws + 18 * M1);    // [18,19.5)
    short* wattno_t= (short*)(ws + 19 * M1 + M1 / 2);  // [19.5,20)
    float* g_all   = ws + 6 * M1;               // [6,14)  phase B
    float* u_all   = ws + 14 * M1;              // [14,22)
    short* h_bf    = (short*)(ws + 22 * M1);    // [22,24)
    short* wt      = (short*)(ws + 24 * M1);    // [24,26)
    short* w2t     = (short*)(ws + 6 * M1);     // [6,8)
    short* wupt    = (short*)(ws + 8 * M1);     // [8,10)
    short* wdownt  = (short*)(ws + 10 * M1);    // [10,11)
    short* hs_bf   = (short*)(ws + 12 * M1);    // [12,12.5)
    float* up      = ws + 14 * M1;              // [14,22)

    const long long EXP_STRIDE = (long long)NEXP * DIM * EDIM;  // 4M

    // ---- phase A: attention ----
    tconv<<<dim3(3072 / 32, DIM / 32, 1), 256, 0, stream>>>(w_attn, 0, wattn_t, 0, DIM, 3 * DIM);
    rmsnorm_kernel<<<TOKENS, 256, 0, stream>>>(x_input, attn_norm_w, xa_bf);
    gemm_bf16<false, false><<<dim3(3072 / 128, TOKENS / 128, 1), 256, 0, stream>>>(
        xa_bf, DIM, 0, wattn_t, DIM, 0, qkv, 3 * DIM, 0, nullptr, TOKENS, 3 * DIM, DIM);
    qkv_post<<<(TOKENS * NHEADS) / 4, 256, 0, stream>>>(qkv, qh_bf, kh_bf);
    vtrans<<<dim3(TOKENS / 32, HEADDIM / 32, NHEADS), 256, 0, stream>>>(qkv, vt_bf);
    attn_kernel<<<dim3(TOKENS / 64, NHEADS, 1), 256, 0, stream>>>(qh_bf, kh_bf, vt_bf, xattn_bf);
    tconv<<<dim3(DIM / 32, DIM / 32, 1), 256, 0, stream>>>(w_attn_o, 0, wattno_t, 0, DIM, DIM);
    gemm_bf16<false, true><<<dim3(DIM / 128, TOKENS / 128, 1), 256, 0, stream>>>(
        xattn_bf, DIM, 0, wattno_t, DIM, 0, xffn, DIM, 0, x_input, TOKENS, DIM, DIM);

    // ---- phase B: router + experts ----
    rmsnorm_kernel<<<TOKENS, 256, 0, stream>>>(xffn, ffn_norm_w, xf_bf);
    router_kernel<<<TOKENS, 256, 0, stream>>>(xf_bf, keys_w, indices, values, w_route);
    tconv<<<dim3(EDIM / 32, DIM / 32, NEXP), 256, 0, stream>>>(
        ffn_experts, (long long)DIM * EDIM, wt, (long long)DIM * EDIM, DIM, EDIM);
    gemm_bf16<false, false><<<dim3(1, TOKENS / 128, NEXP), 256, 0, stream>>>(
        xf_bf, DIM, 0, wt, DIM, (long long)DIM * EDIM, g_all, NEXP * EDIM, EDIM, nullptr,
        TOKENS, EDIM, DIM);
    tconv<<<dim3(EDIM / 32, DIM / 32, NEXP), 256, 0, stream>>>(
        ffn_experts + EXP_STRIDE, (long long)DIM * EDIM, wt, (long long)DIM * EDIM, DIM, EDIM);
    gemm_bf16<false, false><<<dim3(1, TOKENS / 128, NEXP), 256, 0, stream>>>(
        xf_bf, DIM, 0, wt, DIM, (long long)DIM * EDIM, u_all, NEXP * EDIM, EDIM, nullptr,
        TOKENS, EDIM, DIM);
    moe_act_kernel<<<(TOKENS * NEXP * EDIM) / 256, 256, 0, stream>>>(g_all, u_all, w_route, h_bf);
    w2conv<<<(NEXP * DIM * EDIM) / 256, 256, 0, stream>>>(ffn_experts + 2 * EXP_STRIDE, w2t);
    gemm_bf16<false, false><<<dim3(DIM / 128, TOKENS / 128, 1), 256, 0, stream>>>(
        h_bf, NEXP * EDIM, 0, w2t, NEXP * EDIM, 0, ymoe, DIM, 0, nullptr,
        TOKENS, DIM, NEXP * EDIM);

    // ---- phase C: shared expert ----
    tconv<<<dim3((2 * DSHARED) / 32, DIM / 32, 1), 256, 0, stream>>>(w_up, 0, wupt, 0, DIM, 2 * DSHARED);
    gemm_bf16<false, false><<<dim3((2 * DSHARED) / 128, TOKENS / 128, 1), 256, 0, stream>>>(
        xf_bf, DIM, 0, wupt, DIM, 0, up, 2 * DSHARED, 0, nullptr, TOKENS, 2 * DSHARED, DIM);
    swiglu_kernel<<<(TOKENS * DSHARED) / 256, 256, 0, stream>>>(up, hs_bf);
    tconv<<<dim3(DIM / 32, DSHARED / 32, 1), 256, 0, stream>>>(w_down, 0, wdownt, 0, DSHARED, DIM);
    gemm_bf16<true, false><<<dim3(DIM / 128, TOKENS / 128, 1), 256, 0, stream>>>(
        hs_bf, DSHARED, 0, wdownt, DSHARED, 0, ymoe, DIM, 0, nullptr, TOKENS, DIM, DSHARED);

    // ---- final residual ----
    final_add<<<(TOKENS * DIM) / 256, 256, 0, stream>>>(ymoe, xffn, out);
}

// Round 5
// 541.905 us; speedup vs baseline: 4.1963x; 1.1539x over previous
//
#include <hip/hip_runtime.h>
#include <math.h>

#define TOKENS 2048
#define DIM 1024
#define NHEADS 16
#define HEADDIM 64
#define NEXP 32
#define EDIM 128
#define TOPK 8
#define DSHARED 2048
#define RSF_ 2.5f
#define EPS_ 1e-6f

using bf8  = __attribute__((ext_vector_type(8))) short;   // 8 bf16 in 4 VGPRs
using f32x4 = __attribute__((ext_vector_type(4))) float;  // MFMA accumulator

__device__ __forceinline__ short f2bf(float f) {
    unsigned u = __float_as_uint(f);
    unsigned r = (u + 0x7fffu + ((u >> 16) & 1u)) >> 16;
    return (short)r;
}
__device__ __forceinline__ float bf2f(short s) {
    return __uint_as_float(((unsigned)(unsigned short)s) << 16);
}

// Direct global->LDS DMA, 16B per lane. LDS dest = wave-uniform base + lane*16.
__device__ __forceinline__ void async16(const short* g, const short* l) {
    __builtin_amdgcn_global_load_lds(
        (const __attribute__((address_space(1))) void*)(unsigned long long)g,
        (__attribute__((address_space(3))) void*)(unsigned)(unsigned long long)l,
        16, 0, 0);
}

// ---------------- RMSNorm: one block per token, bf16 output ----------------
__global__ __launch_bounds__(256) void rmsnorm_kernel(const float* __restrict__ x,
                                                      const float* __restrict__ w,
                                                      short* __restrict__ out) {
    int row = blockIdx.x;
    const float* xr = x + (long long)row * DIM;
    int t = threadIdx.x;
    float4 xv = ((const float4*)xr)[t];
    float ss = xv.x*xv.x + xv.y*xv.y + xv.z*xv.z + xv.w*xv.w;
    #pragma unroll
    for (int off = 32; off; off >>= 1) ss += __shfl_down(ss, off);
    __shared__ float warps[4];
    if ((t & 63) == 0) warps[t >> 6] = ss;
    __syncthreads();
    float tot = warps[0] + warps[1] + warps[2] + warps[3];
    float scale = rsqrtf(tot / (float)DIM + EPS_);
    float4 wv = ((const float4*)w)[t];
    short4 o;
    o.x = f2bf(xv.x * scale * wv.x);
    o.y = f2bf(xv.y * scale * wv.y);
    o.z = f2bf(xv.z * scale * wv.z);
    o.w = f2bf(xv.w * scale * wv.w);
    ((short4*)(out + (long long)row * DIM))[t] = o;
}

// ---------------- Transpose + convert: fp32 in[K][N] -> bf16 out[N][K] ----------------
__global__ __launch_bounds__(256) void tconv(const float* __restrict__ in, long long sin,
                                             short* __restrict__ out, long long sout,
                                             int K, int N) {
    in  += (long long)blockIdx.z * sin;
    out += (long long)blockIdx.z * sout;
    __shared__ float t[32][33];
    int n0 = blockIdx.x * 32, k0 = blockIdx.y * 32;
    int tx = threadIdx.x & 31, ty = threadIdx.x >> 5;  // ty 0..7
    #pragma unroll
    for (int r = ty; r < 32; r += 8)
        t[r][tx] = in[(long long)(k0 + r) * N + n0 + tx];
    __syncthreads();
    #pragma unroll
    for (int r = ty; r < 32; r += 8)
        out[(long long)(n0 + r) * K + k0 + tx] = f2bf(t[tx][r]);
}

// W2 [e][d][h] fp32 -> bf16 [d][(e*128+h)]
__global__ void w2conv(const float* __restrict__ in, short* __restrict__ out) {
    long long i = (long long)blockIdx.x * 256 + threadIdx.x;  // 4M
    int e = (int)(i >> 17);
    int d = (int)(i >> 7) & 1023;
    int h = (int)(i & 127);
    out[(long long)d * (NEXP * EDIM) + e * EDIM + h] = f2bf(in[i]);
}

// ---------------- bf16 MFMA GEMM: C[M][N] = A[M][K] @ Bt[N][K]^T ----------------
// 128x128 tile, BK=64, XOR-swizzled LDS (conflict-free ds_read_b128),
// async global->LDS staging.
// MODE 0: f32 store, z = batch.  MODE 1: f32 atomicAdd, z = K-split index.
// MODE 2: bf16 store, z = batch.
template<int MODE>
__global__ __launch_bounds__(256) void gemm_bf16(const short* __restrict__ A, int lda, long long sA,
                                                 const short* __restrict__ Bt, int ldb, long long sBt,
                                                 void* __restrict__ Cv, int ldc, long long sC,
                                                 int M, int N, int K) {
    int koff = 0, Ksub = K;
    if (MODE == 1) {
        Ksub = K / gridDim.z;
        koff = blockIdx.z * Ksub;
    } else {
        A  += (long long)blockIdx.z * sA;
        Bt += (long long)blockIdx.z * sBt;
    }
    float* Cf = (float*)Cv;
    short* Cs = (short*)Cv;
    if (MODE != 1) { Cf += (long long)blockIdx.z * sC; Cs += (long long)blockIdx.z * sC; }
    const int m0 = blockIdx.y * 128, n0 = blockIdx.x * 128;
    __shared__ short As[128 * 64];
    __shared__ short Bs[128 * 64];
    const int tid = threadIdx.x, lane = tid & 63, w = tid >> 6;
    const int wm = (w >> 1) * 64, wn = (w & 1) * 64;
    // DMA: wave w stages rows [w*32, w*32+32). Instr c covers rows c*8+drow.
    // Source col XOR-swizzled so LDS(r, j16) holds global chunk j16^(r&7).
    const int drow = lane >> 3;                  // 0..7
    const int dcol = ((lane & 7) ^ drow) * 8;    // swizzled 16B-chunk col, shorts
    const short* ag = A + (long long)(m0 + w * 32 + drow) * lda + koff + dcol;
    const short* bg = Bt + (long long)(n0 + w * 32 + drow) * ldb + koff + dcol;
    const short* lA = As + w * 32 * 64;
    const short* lB = Bs + w * 32 * 64;
    f32x4 acc[4][4];
    #pragma unroll
    for (int i = 0; i < 4; ++i)
        #pragma unroll
        for (int j = 0; j < 4; ++j) { f32x4 z = {0.f, 0.f, 0.f, 0.f}; acc[i][j] = z; }
    const int ra = lane & 15, quad = lane >> 4;
    // fragment chunk (h*4+quad) lives at swizzled col (h*4+quad)^(ra&7)
    const int fs0 = ((quad + 0) ^ (ra & 7)) * 8;
    const int fs1 = ((quad + 4) ^ (ra & 7)) * 8;
    for (int k0 = 0; k0 < Ksub; k0 += 64) {
        #pragma unroll
        for (int c = 0; c < 4; ++c) {
            async16(ag + (long long)(c * 8) * lda + k0, lA + c * 512);
            async16(bg + (long long)(c * 8) * ldb + k0, lB + c * 512);
        }
        __syncthreads();   // drains vmcnt -> tiles resident
        #pragma unroll
        for (int h = 0; h < 2; ++h) {
            const int fs = h ? fs1 : fs0;
            bf8 af[4], bfv[4];
            #pragma unroll
            for (int i = 0; i < 4; ++i) af[i]  = *(const bf8*)(As + (wm + i * 16 + ra) * 64 + fs);
            #pragma unroll
            for (int j = 0; j < 4; ++j) bfv[j] = *(const bf8*)(Bs + (wn + j * 16 + ra) * 64 + fs);
            #pragma unroll
            for (int i = 0; i < 4; ++i)
                #pragma unroll
                for (int j = 0; j < 4; ++j)
                    acc[i][j] = __builtin_amdgcn_mfma_f32_16x16x32_bf16(af[i], bfv[j], acc[i][j], 0, 0, 0);
        }
        __syncthreads();   // reads done before next DMA overwrites
    }
    const int cr = quad * 4, cc = ra;
    #pragma unroll
    for (int i = 0; i < 4; ++i) {
        #pragma unroll
        for (int r = 0; r < 4; ++r) {
            int row = m0 + wm + i * 16 + cr + r;
            long long base = (long long)row * ldc + n0 + wn + cc;
            #pragma unroll
            for (int j = 0; j < 4; ++j) {
                float v = acc[i][j][r];
                if (MODE == 0) Cf[base + j * 16] = v;
                if (MODE == 1) atomicAdd(Cf + base + j * 16, v);
                if (MODE == 2) Cs[base + j * 16] = f2bf(v);
            }
        }
    }
}

// ---------------- zero / copy helpers (float4-vectorized) ----------------
__global__ void zero_f32(float* __restrict__ p) {
    long long i = (long long)blockIdx.x * 256 + threadIdx.x;
    ((float4*)p)[i] = make_float4(0.f, 0.f, 0.f, 0.f);
}
__global__ void copy_f32(float* __restrict__ dst, const float* __restrict__ src) {
    long long i = (long long)blockIdx.x * 256 + threadIdx.x;
    ((float4*)dst)[i] = ((const float4*)src)[i];
}

// ---------------- QKV post: split heads, l2norm(q,k), RoPE -> bf16 [h][s][64] ----------------
__global__ __launch_bounds__(256) void qkv_post(const float* __restrict__ qkv,
                                                short* __restrict__ q,
                                                short* __restrict__ k) {
    int lane = threadIdx.x & 63;
    int sh = blockIdx.x * 4 + (threadIdx.x >> 6);
    int s = sh >> 4;
    int h = sh & 15;
    const float* base = qkv + (long long)s * 3 * DIM;
    float qv = base[h * HEADDIM + lane];
    float kv = base[DIM + h * HEADDIM + lane];
    float qs = qv * qv, ks = kv * kv;
    #pragma unroll
    for (int off = 32; off; off >>= 1) {
        qs += __shfl_xor(qs, off);
        ks += __shfl_xor(ks, off);
    }
    qv /= fmaxf(sqrtf(qs), EPS_);
    kv /= fmaxf(sqrtf(ks), EPS_);
    int i = lane & 31;
    float f = (float)s * powf(10000.0f, -(float)i / 32.0f);
    float c = cosf(f), sn = sinf(f);
    float qo = __shfl_xor(qv, 32);
    float ko = __shfl_xor(kv, 32);
    float sgn = (lane < 32) ? sn : -sn;
    float qr = qv * c + qo * sgn;
    float kr = kv * c + ko * sgn;
    long long o = ((long long)h * TOKENS + s) * HEADDIM + lane;
    q[o] = f2bf(qr);
    k[o] = f2bf(kr);
}

// ---------------- V transpose: qkv fp32 [s][3D] -> vt bf16 [h][64][2048] ----------------
__global__ __launch_bounds__(256) void vtrans(const float* __restrict__ qkv,
                                              short* __restrict__ vt) {
    int h = blockIdx.z;
    int s0 = blockIdx.x * 32, d0 = blockIdx.y * 32;
    __shared__ float t[32][33];
    int tx = threadIdx.x & 31, ty = threadIdx.x >> 5;
    #pragma unroll
    for (int r = ty; r < 32; r += 8)
        t[r][tx] = qkv[(long long)(s0 + r) * (3 * DIM) + 2 * DIM + h * HEADDIM + d0 + tx];
    __syncthreads();
    #pragma unroll
    for (int r = ty; r < 32; r += 8)
        vt[((long long)h * HEADDIM + d0 + r) * TOKENS + s0 + tx] = f2bf(t[tx][r]);
}

// ---------------- MFMA flash attention: 64 q-rows/block, 64-key tiles ----------------
#define ALD 72   // padded LDS row (bf16 units)
__global__ __launch_bounds__(256) void attn_kernel(const short* __restrict__ q,
                                                   const short* __restrict__ k,
                                                   const short* __restrict__ vt,
                                                   short* __restrict__ xo) {
    const int h = blockIdx.y;
    const int q0 = ((int)gridDim.x - 1 - (int)blockIdx.x) * 64;  // longest first
    const int tid = threadIdx.x;
    const int w = tid >> 6, lane = tid & 63;
    const int col = lane & 15, quad = lane >> 4;
    __shared__ short Ks[64 * ALD];
    __shared__ short Vts[64 * ALD];
    __shared__ short Ps[4 * 16 * ALD];
    short* Pw = Ps + w * 16 * ALD;
    const int qbase = q0 + w * 16;
    bf8 qf[2];
    #pragma unroll
    for (int ks = 0; ks < 2; ++ks)
        qf[ks] = *(const bf8*)(q + ((long long)h * TOKENS + qbase + col) * HEADDIM + ks * 32 + quad * 8);
    f32x4 o_[4];
    float m_[4], l_[4];
    #pragma unroll
    for (int n = 0; n < 4; ++n) { f32x4 z = {0.f, 0.f, 0.f, 0.f}; o_[n] = z; }
    #pragma unroll
    for (int r = 0; r < 4; ++r) { m_[r] = -1e30f; l_[r] = 0.f; }
    const int ntiles = q0 / 64 + 1;
    for (int kt = 0; kt < ntiles; ++kt) {
        const int j0 = kt * 64;
        int4 kv[2], vv[2];
        #pragma unroll
        for (int rr = 0; rr < 2; ++rr) {
            int idx = tid + rr * 256;
            int row = idx >> 3, c8 = (idx & 7) * 8;
            kv[rr] = *(const int4*)(k + ((long long)h * TOKENS + j0 + row) * HEADDIM + c8);
            vv[rr] = *(const int4*)(vt + ((long long)h * HEADDIM + row) * TOKENS + j0 + c8);
        }
        __syncthreads();
        #pragma unroll
        for (int rr = 0; rr < 2; ++rr) {
            int idx = tid + rr * 256;
            int row = idx >> 3, c8 = (idx & 7) * 8;
            *(int4*)(Ks + row * ALD + c8) = kv[rr];
            *(int4*)(Vts + row * ALD + c8) = vv[rr];
        }
        __syncthreads();
        f32x4 sacc[4];
        #pragma unroll
        for (int n = 0; n < 4; ++n) { f32x4 z = {0.f, 0.f, 0.f, 0.f}; sacc[n] = z; }
        #pragma unroll
        for (int ks = 0; ks < 2; ++ks) {
            #pragma unroll
            for (int nt = 0; nt < 4; ++nt) {
                bf8 kf = *(const bf8*)(Ks + (nt * 16 + col) * ALD + ks * 32 + quad * 8);
                sacc[nt] = __builtin_amdgcn_mfma_f32_16x16x32_bf16(qf[ks], kf, sacc[nt], 0, 0, 0);
            }
        }
        float sv[4][4];
        const bool diag = (j0 + 64 > qbase);
        #pragma unroll
        for (int nt = 0; nt < 4; ++nt)
            #pragma unroll
            for (int r = 0; r < 4; ++r) {
                float s = sacc[nt][r] * 0.125f;
                if (diag && (j0 + nt * 16 + col > qbase + quad * 4 + r)) s = -1e30f;
                sv[nt][r] = s;
            }
        #pragma unroll
        for (int r = 0; r < 4; ++r) {
            float mx = fmaxf(fmaxf(sv[0][r], sv[1][r]), fmaxf(sv[2][r], sv[3][r]));
            #pragma unroll
            for (int off = 1; off < 16; off <<= 1) mx = fmaxf(mx, __shfl_xor(mx, off));
            float mnew = fmaxf(m_[r], mx);
            float corr = __expf(m_[r] - mnew);
            m_[r] = mnew;
            float psum = 0.f;
            #pragma unroll
            for (int nt = 0; nt < 4; ++nt) {
                float p = __expf(sv[nt][r] - mnew);
                sv[nt][r] = p;
                psum += p;
            }
            #pragma unroll
            for (int off = 1; off < 16; off <<= 1) psum += __shfl_xor(psum, off);
            l_[r] = l_[r] * corr + psum;
            #pragma unroll
            for (int n = 0; n < 4; ++n) o_[n][r] *= corr;
            #pragma unroll
            for (int nt = 0; nt < 4; ++nt)
                Pw[(quad * 4 + r) * ALD + nt * 16 + col] = f2bf(sv[nt][r]);
        }
        #pragma unroll
        for (int ks = 0; ks < 2; ++ks) {
            bf8 pf = *(const bf8*)(Pw + col * ALD + ks * 32 + quad * 8);
            #pragma unroll
            for (int nt = 0; nt < 4; ++nt) {
                bf8 vf = *(const bf8*)(Vts + (nt * 16 + col) * ALD + ks * 32 + quad * 8);
                o_[nt] = __builtin_amdgcn_mfma_f32_16x16x32_bf16(pf, vf, o_[nt], 0, 0, 0);
            }
        }
    }
    #pragma unroll
    for (int nt = 0; nt < 4; ++nt)
        #pragma unroll
        for (int r = 0; r < 4; ++r) {
            int row = qbase + quad * 4 + r;
            xo[(long long)row * DIM + h * HEADDIM + nt * 16 + col] = f2bf(o_[nt][r] / l_[r]);
        }
}

// ---------------- Router (bf16 x input) ----------------
__global__ __launch_bounds__(256) void router_kernel(const short* __restrict__ xf,
                                                     const float* __restrict__ keys_w,
                                                     const int* __restrict__ idx,
                                                     const float* __restrict__ vals,
                                                     float* __restrict__ w_route) {
    int t = blockIdx.x;
    int tid = threadIdx.x;
    int e = tid & 31, c = tid >> 5;
    const short* xr = xf + (long long)t * DIM;
    float p = 0.f;
    for (int j = 0; j < 128; ++j)
        p += bf2f(xr[c * 128 + j]) * keys_w[(c * 128 + j) * NEXP + e];
    __shared__ float part[8][32];
    part[c][e] = p;
    __syncthreads();
    if (tid < NEXP) {
        float lg = 0.f;
        #pragma unroll
        for (int cc = 0; cc < 8; ++cc) lg += part[cc][tid];
        part[0][tid] = lg;
    }
    __syncthreads();
    __shared__ float gate_s[TOPK];
    __shared__ int idx_s[TOPK];
    if (tid < TOPK) {
        int ii = idx[t * TOPK + tid];
        float g = vals[t * TOPK + tid] + part[0][ii];
        gate_s[tid] = (1.0f / (1.0f + __expf(-g))) * RSF_;
        idx_s[tid] = ii;
    }
    __syncthreads();
    if (tid < NEXP) {
        float wr = 0.f;
        #pragma unroll
        for (int kk = 0; kk < TOPK; ++kk)
            if (idx_s[kk] == tid) wr += gate_s[kk];
        w_route[(long long)t * NEXP + tid] = wr;
    }
}

// ---------------- h = silu(g) * u * w_route -> bf16 (gu bf16 [t][e*256 + {g:0-127,u:128-255}]) --
__global__ void moe_act_kernel(const short* __restrict__ gu, const float* __restrict__ w_route,
                               short* __restrict__ hb) {
    long long i = (long long)blockIdx.x * 256 + threadIdx.x;  // 8M = T*NEXP*EDIM
    int t = (int)(i >> 12);
    int e = (int)(i >> 7) & 31;
    int j = (int)(i & 127);
    float gv = bf2f(gu[(long long)t * (NEXP * 256) + e * 256 + j]);
    float uv = bf2f(gu[(long long)t * (NEXP * 256) + e * 256 + 128 + j]);
    float w = w_route[t * NEXP + e];
    float si = gv / (1.0f + __expf(-gv));
    hb[i] = f2bf(si * uv * w);
}

// ---------------- Shared-expert SwiGLU (bf16 in) -> bf16 ----------------
__global__ void swiglu_kernel(const short* __restrict__ up, short* __restrict__ hs) {
    long long i = (long long)blockIdx.x * 256 + threadIdx.x;  // 4M
    int t = (int)(i >> 11), j = (int)(i & 2047);
    float x1 = bf2f(up[(long long)t * (2 * DSHARED) + j]);
    float x2 = bf2f(up[(long long)t * (2 * DSHARED) + DSHARED + j]);
    hs[i] = f2bf(x1 / (1.0f + __expf(-x1)) * x2);
}

// ---------------- Final: out = y_moe + x_ffn_input ----------------
__global__ void final_add(const float* __restrict__ a, const float* __restrict__ b,
                          float* __restrict__ out) {
    long long i = (long long)blockIdx.x * 256 + threadIdx.x;  // 2M
    out[i] = a[i] + b[i];
}

extern "C" void kernel_launch(void* const* d_in, const int* in_sizes, int n_in,
                              void* d_out, int out_size, void* d_ws, size_t ws_size,
                              hipStream_t stream) {
    (void)in_sizes; (void)n_in; (void)out_size; (void)ws_size;
    const float* x_input     = (const float*)d_in[0];
    const int*   indices     = (const int*)d_in[1];
    const float* values      = (const float*)d_in[2];
    const float* w_attn      = (const float*)d_in[3];
    const float* w_attn_o    = (const float*)d_in[4];
    const float* attn_norm_w = (const float*)d_in[5];
    const float* ffn_norm_w  = (const float*)d_in[6];
    const float* ffn_experts = (const float*)d_in[7];
    const float* keys_w      = (const float*)d_in[8];
    const float* w_up        = (const float*)d_in[9];
    const float* w_down      = (const float*)d_in[10];
    float* out = (float*)d_out;
    float* ws  = (float*)d_ws;

    const long long M1 = 1024 * 1024;
    // Workspace (float units, lifetime-aliased; max extent 24M floats = 96MB):
    float* xffn    = ws + 0 * M1;                     // [0,2)   x_input + attn_o (atomic)
    float* ymoe    = ws + 2 * M1;                     // [2,4)   atomic accumulator
    short* xa_bf   = (short*)(ws + 4 * M1);           // [4,4.5)
    short* xf_bf   = (short*)(ws + 4 * M1 + M1 / 2);  // [4.5,5)
    short* xattn_bf= (short*)(ws + 5 * M1);           // [5,5.5)
    float* w_route = ws + 5 * M1 + M1 / 2;            // [5.5,5.6)
    float* qkv     = ws + 6 * M1;                     // [6,12)   phase A
    short* qh_bf   = (short*)(ws + 12 * M1);          // [12,12.5)
    short* kh_bf   = (short*)(ws + 12 * M1 + M1 / 2); // [12.5,13)
    short* vt_bf   = (short*)(ws + 13 * M1);          // [13,13.5)
    short* wattn_t = (short*)(ws + 14 * M1);          // [14,15.5)
    short* wattno_t= (short*)(ws + 15 * M1 + M1 / 2); // [15.5,16)
    short* wgu     = (short*)(ws + 6 * M1);           // [6,10)   phase B (qkv dead)
    short* gu_bf   = (short*)(ws + 10 * M1);          // [10,18)
    short* h_bf    = (short*)(ws + 18 * M1);          // [18,22)
    short* w2t     = (short*)(ws + 22 * M1);          // [22,24)
    short* wupt    = (short*)(ws + 6 * M1);           // [6,8)    phase C (wgu dead)
    short* up_bf   = (short*)(ws + 10 * M1);          // [10,14)  (gu_bf dead)
    short* hs_bf   = (short*)(ws + 14 * M1);          // [14,16)
    short* wdownt  = (short*)(ws + 16 * M1);          // [16,17)

    const long long EXP_STRIDE = (long long)NEXP * DIM * EDIM;  // 4M

    // ---- phase A: attention ----
    tconv<<<dim3(3072 / 32, DIM / 32, 1), 256, 0, stream>>>(w_attn, 0, wattn_t, 0, DIM, 3 * DIM);
    rmsnorm_kernel<<<TOKENS, 256, 0, stream>>>(x_input, attn_norm_w, xa_bf);
    gemm_bf16<0><<<dim3(3072 / 128, TOKENS / 128, 1), 256, 0, stream>>>(
        xa_bf, DIM, 0, wattn_t, DIM, 0, qkv, 3 * DIM, 0, TOKENS, 3 * DIM, DIM);
    qkv_post<<<(TOKENS * NHEADS) / 4, 256, 0, stream>>>(qkv, qh_bf, kh_bf);
    vtrans<<<dim3(TOKENS / 32, HEADDIM / 32, NHEADS), 256, 0, stream>>>(qkv, vt_bf);
    attn_kernel<<<dim3(TOKENS / 64, NHEADS, 1), 256, 0, stream>>>(qh_bf, kh_bf, vt_bf, xattn_bf);
    tconv<<<dim3(DIM / 32, DIM / 32, 1), 256, 0, stream>>>(w_attn_o, 0, wattno_t, 0, DIM, DIM);
    copy_f32<<<(TOKENS * DIM) / 1024, 256, 0, stream>>>(xffn, x_input);   // residual pre-init
    gemm_bf16<1><<<dim3(DIM / 128, TOKENS / 128, 4), 256, 0, stream>>>(
        xattn_bf, DIM, 0, wattno_t, DIM, 0, xffn, DIM, 0, TOKENS, DIM, DIM);

    // ---- phase B: router + experts ----
    rmsnorm_kernel<<<TOKENS, 256, 0, stream>>>(xffn, ffn_norm_w, xf_bf);
    router_kernel<<<TOKENS, 256, 0, stream>>>(xf_bf, keys_w, indices, values, w_route);
    // Wgu[e] = [256][1024]: rows 0-127 = W0[e]^T, 128-255 = W1[e]^T
    tconv<<<dim3(EDIM / 32, DIM / 32, NEXP), 256, 0, stream>>>(
        ffn_experts, (long long)DIM * EDIM, wgu, 256 * 1024, DIM, EDIM);
    tconv<<<dim3(EDIM / 32, DIM / 32, NEXP), 256, 0, stream>>>(
        ffn_experts + EXP_STRIDE, (long long)DIM * EDIM, wgu + 128 * 1024, 256 * 1024, DIM, EDIM);
    gemm_bf16<2><<<dim3(2, TOKENS / 128, NEXP), 256, 0, stream>>>(
        xf_bf, DIM, 0, wgu, DIM, 256 * 1024, gu_bf, NEXP * 256, 256, TOKENS, 256, DIM);
    moe_act_kernel<<<(TOKENS * NEXP * EDIM) / 256, 256, 0, stream>>>(gu_bf, w_route, h_bf);
    w2conv<<<(NEXP * DIM * EDIM) / 256, 256, 0, stream>>>(ffn_experts + 2 * EXP_STRIDE, w2t);
    zero_f32<<<(TOKENS * DIM) / 1024, 256, 0, stream>>>(ymoe);
    gemm_bf16<1><<<dim3(DIM / 128, TOKENS / 128, 4), 256, 0, stream>>>(
        h_bf, NEXP * EDIM, 0, w2t, NEXP * EDIM, 0, ymoe, DIM, 0, TOKENS, DIM, NEXP * EDIM);

    // ---- phase C: shared expert ----
    tconv<<<dim3((2 * DSHARED) / 32, DIM / 32, 1), 256, 0, stream>>>(w_up, 0, wupt, 0, DIM, 2 * DSHARED);
    gemm_bf16<2><<<dim3((2 * DSHARED) / 128, TOKENS / 128, 1), 256, 0, stream>>>(
        xf_bf, DIM, 0, wupt, DIM, 0, up_bf, 2 * DSHARED, 0, TOKENS, 2 * DSHARED, DIM);
    swiglu_kernel<<<(TOKENS * DSHARED) / 256, 256, 0, stream>>>(up_bf, hs_bf);
    tconv<<<dim3(DIM / 32, DSHARED / 32, 1), 256, 0, stream>>>(w_down, 0, wdownt, 0, DSHARED, DIM);
    gemm_bf16<1><<<dim3(DIM / 128, TOKENS / 128, 4), 256, 0, stream>>>(
        hs_bf, DSHARED, 0, wdownt, DSHARED, 0, ymoe, DIM, 0, TOKENS, DIM, DSHARED);

    // ---- final residual ----
    final_add<<<(TOKENS * DIM) / 256, 256, 0, stream>>>(ymoe, xffn, out);
}